// Round 5
// baseline (898.097 us; speedup 1.0000x reference)
//
#include <hip/hip_runtime.h>
#include <hip/hip_bf16.h>
#include <math.h>

#define BB     2
#define SS     2048
#define HH     768
#define NHEAD  12
#define DHEAD  64
#define FFD    3072
#define NLAYER 2
#define MTOK   (BB*SS)   // 4096 rows

typedef __attribute__((ext_vector_type(8))) short bf16x8;
typedef __attribute__((ext_vector_type(4))) float f32x4;

__device__ __forceinline__ short f2bs(float f) {
    union { float f; unsigned u; } v; v.f = f;
    unsigned r = v.u + 0x7FFF + ((v.u >> 16) & 1);   // RNE to bf16
    return (short)(r >> 16);
}
__device__ __forceinline__ float bs2f(short s) {
    union { unsigned u; float f; } v; v.u = ((unsigned)(unsigned short)s) << 16;
    return v.f;
}
// async 16B/lane global->LDS (lds dst = wave-uniform base + lane*16)
__device__ __forceinline__ void gl2lds16(const short* g, short* l) {
    __builtin_amdgcn_global_load_lds(
        (const __attribute__((address_space(1))) unsigned int*)g,
        (__attribute__((address_space(3))) unsigned int*)l, 16, 0, 0);
}

// ---------------------------------------------------------------------------
// Prep: Wt[n*K+k] = bf16(W[k*N+n]). 32x32 tile, 256 thr (32x8).
// ---------------------------------------------------------------------------
__global__ __launch_bounds__(256)
void transpose_cvt(const float* __restrict__ W, short* __restrict__ Wt, int K, int N)
{
    __shared__ short tile[32][33];
    const int k0 = blockIdx.x * 32, n0 = blockIdx.y * 32;
    const int tx = threadIdx.x & 31, ty = threadIdx.x >> 5;
#pragma unroll
    for (int i = 0; i < 4; i++)
        tile[ty + i*8][tx] = f2bs(W[(size_t)(k0 + ty + i*8) * N + n0 + tx]);
    __syncthreads();
#pragma unroll
    for (int i = 0; i < 4; i++)
        Wt[(size_t)(n0 + ty + i*8) * K + k0 + tx] = tile[tx][ty + i*8];
}

// Prep: dst = bf16(src * (*scalep or 1))
__global__ __launch_bounds__(256)
void cvt_scale(const float* __restrict__ src, const float* __restrict__ scalep,
               short* __restrict__ dst, int n)
{
    const int i = blockIdx.x * 256 + threadIdx.x;
    const float s = scalep ? scalep[0] : 1.f;
    if (i < n) dst[i] = f2bs(src[i] * s);
}

// ---------------------------------------------------------------------------
// C[M,N](bf16) = act(A[M,K](bf16) @ Bt[N,K](bf16)^T + bias[N](f32))
// m97 recipe: 128x128 tile, BK=32, 4 waves, 16x16x32 MFMA, global_load_lds.
// Cols >= vsplit are written TRANSPOSED to VtOut[col-vsplit][row] (ushort4,
// rows g*4+r consecutive) -- used by the QKV GEMM to emit V^T for attention.
// ---------------------------------------------------------------------------
__global__ __launch_bounds__(256)
void gemm_mfma(const short* __restrict__ A, const short* __restrict__ Bt,
               const float* __restrict__ bias, short* __restrict__ C, int ldc,
               int M, int N, int K, int gelu, short* __restrict__ VtOut, int vsplit)
{
    __shared__ short sA[128*32];
    __shared__ short sB[128*32];
    const int tid  = threadIdx.x;
    const int w    = tid >> 6;
    const int lane = tid & 63;
    const int l16  = lane & 15, g = lane >> 4;
    const int wm   = w & 1, wn = w >> 1;
    const size_t m0 = (size_t)blockIdx.y * 128, n0 = (size_t)blockIdx.x * 128;

    const int srow = lane >> 2;
    const int kc   = lane & 3;

    f32x4 acc[4][4];
#pragma unroll
    for (int i = 0; i < 4; i++)
#pragma unroll
        for (int j = 0; j < 4; j++) acc[i][j] = (f32x4){0.f,0.f,0.f,0.f};

    const short* gA0 = A  + (m0 + w*32 +      srow) * (size_t)K + kc*8;
    const short* gA1 = A  + (m0 + w*32 + 16 + srow) * (size_t)K + kc*8;
    const short* gB0 = Bt + (n0 + w*32 +      srow) * (size_t)K + kc*8;
    const short* gB1 = Bt + (n0 + w*32 + 16 + srow) * (size_t)K + kc*8;
    short* lA0 = &sA[(w*32     )*32];
    short* lA1 = &sA[(w*32 + 16)*32];
    short* lB0 = &sB[(w*32     )*32];
    short* lB1 = &sB[(w*32 + 16)*32];

    for (int k0 = 0; k0 < K; k0 += 32) {
        gl2lds16(gA0 + k0, lA0);
        gl2lds16(gA1 + k0, lA1);
        gl2lds16(gB0 + k0, lB0);
        gl2lds16(gB1 + k0, lB1);
        __syncthreads();

        bf16x8 af[4], bfr[4];
#pragma unroll
        for (int mt = 0; mt < 4; mt++)
            af[mt] = *(const bf16x8*)&sA[(wm*64 + mt*16 + l16)*32 + g*8];
#pragma unroll
        for (int nt = 0; nt < 4; nt++)
            bfr[nt] = *(const bf16x8*)&sB[(wn*64 + nt*16 + l16)*32 + g*8];
#pragma unroll
        for (int mt = 0; mt < 4; mt++)
#pragma unroll
            for (int nt = 0; nt < 4; nt++)
                acc[mt][nt] = __builtin_amdgcn_mfma_f32_16x16x32_bf16(
                                  af[mt], bfr[nt], acc[mt][nt], 0, 0, 0);
        __syncthreads();
    }

#pragma unroll
    for (int mt = 0; mt < 4; mt++) {
        const size_t row0 = m0 + wm*64 + mt*16 + g*4;
#pragma unroll
        for (int nt = 0; nt < 4; nt++) {
            const size_t col = n0 + wn*64 + nt*16 + l16;
            if ((int)col >= vsplit) {           // V part -> transposed bf16 out
                short4 t;
                t.x = f2bs(acc[mt][nt][0] + bias[col]);
                t.y = f2bs(acc[mt][nt][1] + bias[col]);
                t.z = f2bs(acc[mt][nt][2] + bias[col]);
                t.w = f2bs(acc[mt][nt][3] + bias[col]);
                *(short4*)&VtOut[(size_t)(col - vsplit)*MTOK + row0] = t;
            } else {
#pragma unroll
                for (int r = 0; r < 4; r++) {
                    float v = acc[mt][nt][r] + bias[col];
                    if (gelu) v = 0.5f * v * (1.f + erff(v * 0.70710678118f));
                    C[(row0 + r) * (size_t)ldc + col] = f2bs(v);
                }
            }
        }
    }
}

// ---------------------------------------------------------------------------
// 128x64-tile variant for N=768 GEMMs (grid 384 blocks vs 192).
// Wave tile 64x32 (acc[4][2]), BK=32.
// ---------------------------------------------------------------------------
__global__ __launch_bounds__(256)
void gemm_mfma_n64(const short* __restrict__ A, const short* __restrict__ Bt,
                   const float* __restrict__ bias, short* __restrict__ C, int ldc,
                   int M, int N, int K, int gelu)
{
    __shared__ short sA[128*32];
    __shared__ short sB[64*32];
    const int tid  = threadIdx.x;
    const int w    = tid >> 6;
    const int lane = tid & 63;
    const int l16  = lane & 15, g = lane >> 4;
    const int wm   = w & 1, wn = w >> 1;
    const size_t m0 = (size_t)blockIdx.y * 128, n0 = (size_t)blockIdx.x * 64;

    const int srow = lane >> 2;
    const int kc   = lane & 3;

    f32x4 acc[4][2];
#pragma unroll
    for (int i = 0; i < 4; i++)
#pragma unroll
        for (int j = 0; j < 2; j++) acc[i][j] = (f32x4){0.f,0.f,0.f,0.f};

    const short* gA0 = A  + (m0 + w*32 +      srow) * (size_t)K + kc*8;
    const short* gA1 = A  + (m0 + w*32 + 16 + srow) * (size_t)K + kc*8;
    const short* gB0 = Bt + (n0 + w*16 +      srow) * (size_t)K + kc*8;
    short* lA0 = &sA[(w*32     )*32];
    short* lA1 = &sA[(w*32 + 16)*32];
    short* lB0 = &sB[(w*16     )*32];

    for (int k0 = 0; k0 < K; k0 += 32) {
        gl2lds16(gA0 + k0, lA0);
        gl2lds16(gA1 + k0, lA1);
        gl2lds16(gB0 + k0, lB0);
        __syncthreads();

        bf16x8 af[4], bfr[2];
#pragma unroll
        for (int mt = 0; mt < 4; mt++)
            af[mt] = *(const bf16x8*)&sA[(wm*64 + mt*16 + l16)*32 + g*8];
#pragma unroll
        for (int nt = 0; nt < 2; nt++)
            bfr[nt] = *(const bf16x8*)&sB[(wn*32 + nt*16 + l16)*32 + g*8];
#pragma unroll
        for (int mt = 0; mt < 4; mt++)
#pragma unroll
            for (int nt = 0; nt < 2; nt++)
                acc[mt][nt] = __builtin_amdgcn_mfma_f32_16x16x32_bf16(
                                  af[mt], bfr[nt], acc[mt][nt], 0, 0, 0);
        __syncthreads();
    }

#pragma unroll
    for (int mt = 0; mt < 4; mt++) {
        const size_t row0 = m0 + wm*64 + mt*16 + g*4;
#pragma unroll
        for (int nt = 0; nt < 2; nt++) {
            const size_t col = n0 + wn*32 + nt*16 + l16;
#pragma unroll
            for (int r = 0; r < 4; r++) {
                float v = acc[mt][nt][r] + bias[col];
                if (gelu) v = 0.5f * v * (1.f + erff(v * 0.70710678118f));
                C[(row0 + r) * (size_t)ldc + col] = f2bs(v);
            }
        }
    }
}

// ---------------------------------------------------------------------------
// Flash attention, barrier-free K-loop. QK packed [M][1536] (Q|K), Vt [768][M].
// B-frags for QK^T and PV are loaded DIRECT from global (K is dim-contiguous,
// Vt is key-contiguous). sP is written+read by the SAME wave only -> no
// __syncthreads in the loop. Mask staged once.
// ---------------------------------------------------------------------------
__global__ __launch_bounds__(256)
void attn_fused(const short* __restrict__ QK, const short* __restrict__ Vt,
                const float* __restrict__ mask, const short* __restrict__ bC,
                short* __restrict__ CTX)
{
    __shared__ float sMask[SS];     // 8 KB
    __shared__ short sP[64*72];     // 9.2 KB, per-wave rows

    const int q0  = blockIdx.x * 64;
    const int h   = blockIdx.y;
    const int b   = blockIdx.z;
    const int tid = threadIdx.x;
    const int w   = tid >> 6;
    const int lane = tid & 63;
    const int l16 = lane & 15;
    const int g   = lane >> 4;
    const float scale = 0.125f;

    for (int k = tid; k < SS; k += 256)
        sMask[k] = (1.f - mask[b*SS + k]) * (-10000.0f);

    // Q A-frags (held all kernel)
    const short* qrow = QK + ((size_t)(b*SS) + q0 + w*16 + l16) * 1536 + h*64;
    bf16x8 aQ0 = *(const bf16x8*)(qrow + g*8);
    bf16x8 aQ1 = *(const bf16x8*)(qrow + 32 + g*8);

    f32x4 O[4];
#pragma unroll
    for (int d = 0; d < 4; d++) O[d] = (f32x4){0.f,0.f,0.f,0.f};
    float m_i[4], l_i[4];
#pragma unroll
    for (int r = 0; r < 4; r++) { m_i[r] = -1e30f; l_i[r] = 0.f; }

    const short* Kbase = QK + (size_t)(b*SS)*1536 + 768 + h*64;  // + key*1536
    const short* Vbase = Vt + (size_t)(h*64)*MTOK + b*SS;        // + dim*MTOK + key
    const short* bCq   = bC + (size_t)(q0 + w*16 + g*4)*SS;      // + r*SS + k

    __syncthreads();   // sMask ready (only barrier)

    for (int k0 = 0; k0 < SS; k0 += 64) {
        // ---- S = QK^T*scale + bias + mask, B-frags direct from global ----
        float S[4][4];
#pragma unroll
        for (int t16 = 0; t16 < 4; t16++) {
            const short* krow = Kbase + (size_t)(k0 + t16*16 + l16) * 1536;
            bf16x8 b0 = *(const bf16x8*)(krow + g*8);
            bf16x8 b1 = *(const bf16x8*)(krow + 32 + g*8);
            f32x4 c = (f32x4){0.f,0.f,0.f,0.f};
            c = __builtin_amdgcn_mfma_f32_16x16x32_bf16(aQ0, b0, c, 0, 0, 0);
            c = __builtin_amdgcn_mfma_f32_16x16x32_bf16(aQ1, b1, c, 0, 0, 0);
            const int   kcol = k0 + t16*16 + l16;
            const float madd = sMask[kcol];
#pragma unroll
            for (int r = 0; r < 4; r++)
                S[t16][r] = c[r]*scale + bs2f(bCq[(size_t)r*SS + kcol]) + madd;
        }

        // ---- online softmax, all in regs ----
#pragma unroll
        for (int r = 0; r < 4; r++) {
            float mx = fmaxf(fmaxf(S[0][r], S[1][r]), fmaxf(S[2][r], S[3][r]));
            mx = fmaxf(mx, __shfl_xor(mx, 1));
            mx = fmaxf(mx, __shfl_xor(mx, 2));
            mx = fmaxf(mx, __shfl_xor(mx, 4));
            mx = fmaxf(mx, __shfl_xor(mx, 8));
            const float mnew  = fmaxf(m_i[r], mx);
            const float alpha = __expf(m_i[r] - mnew);
            float rs = 0.f;
#pragma unroll
            for (int t16 = 0; t16 < 4; t16++) {
                float p = __expf(S[t16][r] - mnew);
                S[t16][r] = p;
                rs += p;
            }
            rs += __shfl_xor(rs, 1);
            rs += __shfl_xor(rs, 2);
            rs += __shfl_xor(rs, 4);
            rs += __shfl_xor(rs, 8);
            l_i[r] = l_i[r]*alpha + rs;
            m_i[r] = mnew;
#pragma unroll
            for (int d = 0; d < 4; d++) O[d][r] *= alpha;
        }

        // ---- P: C-layout -> A-layout via per-wave LDS rows (no barrier) ----
#pragma unroll
        for (int t16 = 0; t16 < 4; t16++)
#pragma unroll
            for (int r = 0; r < 4; r++)
                sP[(w*16 + g*4 + r)*72 + t16*16 + l16] = f2bs(S[t16][r]);

        bf16x8 aP0 = *(const bf16x8*)&sP[(w*16 + l16)*72 + g*8];
        bf16x8 aP1 = *(const bf16x8*)&sP[(w*16 + l16)*72 + 32 + g*8];

        // ---- O += P @ V, V B-frags direct from global Vt ----
#pragma unroll
        for (int d = 0; d < 4; d++) {
            const short* vrow = Vbase + (size_t)(d*16 + l16)*MTOK + k0;
            bf16x8 v0 = *(const bf16x8*)(vrow + g*8);
            bf16x8 v1 = *(const bf16x8*)(vrow + 32 + g*8);
            O[d] = __builtin_amdgcn_mfma_f32_16x16x32_bf16(aP0, v0, O[d], 0, 0, 0);
            O[d] = __builtin_amdgcn_mfma_f32_16x16x32_bf16(aP1, v1, O[d], 0, 0, 0);
        }
    }

#pragma unroll
    for (int d = 0; d < 4; d++)
#pragma unroll
        for (int r = 0; r < 4; r++)
            CTX[((size_t)(b*SS) + q0 + w*16 + g*4 + r)*HH + h*64 + d*16 + l16]
                = f2bs(O[d][r] / l_i[r]);
}

// ---------------------------------------------------------------------------
// Out(bf16) = LayerNorm(A + R) * g + beta; optional fp32 copy to OutF.
// ---------------------------------------------------------------------------
__global__ __launch_bounds__(256)
void add_ln(const short* __restrict__ A, const short* __restrict__ R,
            const float* __restrict__ g, const float* __restrict__ beta,
            short* __restrict__ Out, float* __restrict__ OutF)
{
    const int row = blockIdx.x;
    const int tid = threadIdx.x;
    __shared__ float vals[HH];
    __shared__ float rbuf[256];

    float s = 0.f;
    for (int c = tid; c < HH; c += 256) {
        float v = bs2f(A[(size_t)row*HH + c]) + bs2f(R[(size_t)row*HH + c]);
        vals[c] = v;
        s += v;
    }
    rbuf[tid] = s; __syncthreads();
    for (int off = 128; off > 0; off >>= 1) {
        if (tid < off) rbuf[tid] += rbuf[tid + off];
        __syncthreads();
    }
    const float mu = rbuf[0] * (1.f / HH); __syncthreads();

    float s2 = 0.f;
    for (int c = tid; c < HH; c += 256) {
        float d = vals[c] - mu;
        s2 += d * d;
    }
    rbuf[tid] = s2; __syncthreads();
    for (int off = 128; off > 0; off >>= 1) {
        if (tid < off) rbuf[tid] += rbuf[tid + off];
        __syncthreads();
    }
    const float rstd = rsqrtf(rbuf[0] * (1.f / HH) + 1e-12f); __syncthreads();

    for (int c = tid; c < HH; c += 256) {
        float v = (vals[c] - mu) * rstd * g[c] + beta[c];
        Out[(size_t)row*HH + c] = f2bs(v);
        if (OutF) OutF[(size_t)row*HH + c] = v;
    }
}

// ---------------------------------------------------------------------------
extern "C" void kernel_launch(void* const* d_in, const int* in_sizes, int n_in,
                              void* d_out, int out_size, void* d_ws, size_t ws_size,
                              hipStream_t stream)
{
    const float* hs    = (const float*)d_in[0];
    const float* mask  = (const float*)d_in[1];
    const float* biasM = (const float*)d_in[2];
    const float* coef  = (const float*)d_in[3];
    const float* Wq    = (const float*)d_in[4];
    const float* bq    = (const float*)d_in[5];
    const float* Wk    = (const float*)d_in[6];
    const float* bk    = (const float*)d_in[7];
    const float* Wv    = (const float*)d_in[8];
    const float* bv    = (const float*)d_in[9];
    const float* Wo    = (const float*)d_in[10];
    const float* bo    = (const float*)d_in[11];
    const float* ln1g  = (const float*)d_in[12];
    const float* ln1b  = (const float*)d_in[13];
    const float* Wi    = (const float*)d_in[14];
    const float* bi    = (const float*)d_in[15];
    const float* Wo2   = (const float*)d_in[16];
    const float* bo2   = (const float*)d_in[17];
    const float* ln2g  = (const float*)d_in[18];
    const float* ln2b  = (const float*)d_in[19];

    // ---- workspace (74.5 MB, same footprint as R4's proven layout) ----
    const size_t sH   = (size_t)MTOK * HH;        // 3,145,728
    const size_t sQK  = (size_t)MTOK * 1536;      // 6,291,456
    const size_t sVt  = (size_t)HH * MTOK;        // 3,145,728
    const size_t WPL  = 7077888;                  // bf16 weight elems per layer
    short* wt   = (short*)d_ws;                   // [2*WPL]
    float* bqkv = (float*)(wt + 2*WPL);           // [2*2304]
    short* bC   = (short*)(bqkv + 2*2304);        // [SS*SS]
    short* X    = bC + (size_t)SS*SS;
    short* X2   = X  + sH;
    short* QK   = X2 + sH;                        // Q|K packed [M][1536]
    short* Vt   = QK + sQK;                       // V transposed [768][M]
    short* CTX  = Vt + sVt;                       // end = CTX + sH
    short* TMP  = QK;                             // alias (QK dead post-attn)
    short* INTER= QK;                             // alias: QK+Vt+CTX = MTOK*FFD
    short* TMP2 = X;                              // alias (X dead)

    const dim3 blk(256);

    // ---- prep: weights -> bf16 transposed; bias_matrix*coef; hs -> bf16 ----
    for (int l = 0; l < NLAYER; l++) {
        short* wl = wt + (size_t)l * WPL;
        short* qkvt = wl;                         // [2304][768]
        short* wot  = wl + 1769472;               // [768][768]
        short* wit  = wl + 2359296;               // [3072][768]
        short* wo2t = wl + 4718592;               // [768][3072]
        transpose_cvt<<<dim3(24,24), blk, 0, stream>>>(Wq + (size_t)l*HH*HH, qkvt,            HH, HH);
        transpose_cvt<<<dim3(24,24), blk, 0, stream>>>(Wk + (size_t)l*HH*HH, qkvt + 768*768,  HH, HH);
        transpose_cvt<<<dim3(24,24), blk, 0, stream>>>(Wv + (size_t)l*HH*HH, qkvt + 1536*768, HH, HH);
        transpose_cvt<<<dim3(24,24), blk, 0, stream>>>(Wo + (size_t)l*HH*HH, wot,             HH, HH);
        transpose_cvt<<<dim3(24,96), blk, 0, stream>>>(Wi + (size_t)l*HH*FFD, wit,            HH, FFD);
        transpose_cvt<<<dim3(96,24), blk, 0, stream>>>(Wo2+ (size_t)l*FFD*HH, wo2t,           FFD, HH);
        hipMemcpyAsync(bqkv + l*2304,        bq + l*HH, HH*4, hipMemcpyDeviceToDevice, stream);
        hipMemcpyAsync(bqkv + l*2304 + 768,  bk + l*HH, HH*4, hipMemcpyDeviceToDevice, stream);
        hipMemcpyAsync(bqkv + l*2304 + 1536, bv + l*HH, HH*4, hipMemcpyDeviceToDevice, stream);
    }
    cvt_scale<<<dim3((SS*SS + 255)/256), blk, 0, stream>>>(biasM, coef, bC, SS*SS);
    cvt_scale<<<dim3((int)((sH + 255)/256)), blk, 0, stream>>>(hs, nullptr, X, (int)sH);

    const dim3 gQKV(2304/128, MTOK/128);   // [18, 32]
    const dim3 gH64(HH/64,    MTOK/128);   // [12, 32] N=768 GEMMs
    const dim3 gFF (FFD/128,  MTOK/128);   // [24, 32]
    const dim3 gA  (SS/64, NHEAD, BB);     // [32, 12, 2]
    const int NOSPLIT = 1 << 30;

    for (int l = 0; l < NLAYER; l++) {
        short* wl = wt + (size_t)l * WPL;
        // QKV: Q|K cols -> QK [M][1536], V cols -> Vt [768][M] (transposed)
        gemm_mfma<<<gQKV, blk, 0, stream>>>(X, wl, bqkv + l*2304, QK, 1536,
                                            MTOK, 2304, HH, 0, Vt, 1536);
        attn_fused<<<gA, blk, 0, stream>>>(QK, Vt, mask, bC, CTX);
        gemm_mfma_n64<<<gH64, blk, 0, stream>>>(CTX, wl + 1769472, bo + l*HH, TMP, HH,
                                                MTOK, HH, HH, 0);
        add_ln<<<MTOK, blk, 0, stream>>>(TMP, X, ln1g + l*HH, ln1b + l*HH, X2, nullptr);
        gemm_mfma<<<gFF, blk, 0, stream>>>(X2, wl + 2359296, bi + l*FFD, INTER, FFD,
                                           MTOK, FFD, HH, 1, nullptr, NOSPLIT);
        gemm_mfma_n64<<<gH64, blk, 0, stream>>>(INTER, wl + 4718592, bo2 + l*HH, TMP2, HH,
                                                MTOK, HH, FFD, 0);
        add_ln<<<MTOK, blk, 0, stream>>>(TMP2, X2, ln2g + l*HH, ln2b + l*HH, X,
                                         (l == NLAYER-1) ? (float*)d_out : nullptr);
    }
}

// Round 6
// 781.874 us; speedup vs baseline: 1.1486x; 1.1486x over previous
//
#include <hip/hip_runtime.h>
#include <hip/hip_bf16.h>
#include <math.h>

#define BB     2
#define SS     2048
#define HH     768
#define NHEAD  12
#define DHEAD  64
#define FFD    3072
#define NLAYER 2
#define MTOK   (BB*SS)   // 4096 rows

typedef __attribute__((ext_vector_type(8))) short bf16x8;
typedef __attribute__((ext_vector_type(4))) short bf16x4;
typedef __attribute__((ext_vector_type(4))) float f32x4;

__device__ __forceinline__ short f2bs(float f) {
    union { float f; unsigned u; } v; v.f = f;
    unsigned r = v.u + 0x7FFF + ((v.u >> 16) & 1);   // RNE to bf16
    return (short)(r >> 16);
}
__device__ __forceinline__ float bs2f(short s) {
    union { unsigned u; float f; } v; v.u = ((unsigned)(unsigned short)s) << 16;
    return v.f;
}
// async 16B/lane global->LDS (lds dst = wave-uniform base + lane*16)
__device__ __forceinline__ void gl2lds16(const short* g, short* l) {
    __builtin_amdgcn_global_load_lds(
        (const __attribute__((address_space(1))) unsigned int*)g,
        (__attribute__((address_space(3))) unsigned int*)l, 16, 0, 0);
}

// ---------------------------------------------------------------------------
// Prep: Wt[n*K+k] = bf16(W[k*N+n] * (*scalep or 1)). 32x32 tile, 256 thr.
// ---------------------------------------------------------------------------
__global__ __launch_bounds__(256)
void transpose_cvt(const float* __restrict__ W, short* __restrict__ Wt,
                   int K, int N, const float* __restrict__ scalep)
{
    __shared__ short tile[32][33];
    const int k0 = blockIdx.x * 32, n0 = blockIdx.y * 32;
    const int tx = threadIdx.x & 31, ty = threadIdx.x >> 5;
    const float s = scalep ? scalep[0] : 1.f;
#pragma unroll
    for (int i = 0; i < 4; i++)
        tile[ty + i*8][tx] = f2bs(W[(size_t)(k0 + ty + i*8) * N + n0 + tx] * s);
    __syncthreads();
#pragma unroll
    for (int i = 0; i < 4; i++)
        Wt[(size_t)(n0 + ty + i*8) * K + k0 + tx] = tile[tx][ty + i*8];
}

// Prep: dst = bf16(src)
__global__ __launch_bounds__(256)
void cvt_bf16(const float* __restrict__ src, short* __restrict__ dst, int n)
{
    const int i = blockIdx.x * 256 + threadIdx.x;
    if (i < n) dst[i] = f2bs(src[i]);
}

// ---------------------------------------------------------------------------
// C[M,N](bf16) = act(A[M,K](bf16) @ Bt[N,K](bf16)^T + bias[N](f32))
// m97 recipe: 128x128 tile, BK=32, 4 waves, 16x16x32 MFMA, global_load_lds.
// Cols >= vsplit are written TRANSPOSED to VtOut[col-vsplit][row] (short4).
// ---------------------------------------------------------------------------
__global__ __launch_bounds__(256)
void gemm_mfma(const short* __restrict__ A, const short* __restrict__ Bt,
               const float* __restrict__ bias, short* __restrict__ C, int ldc,
               int M, int N, int K, int gelu, short* __restrict__ VtOut, int vsplit)
{
    __shared__ short sA[128*32];
    __shared__ short sB[128*32];
    const int tid  = threadIdx.x;
    const int w    = tid >> 6;
    const int lane = tid & 63;
    const int l16  = lane & 15, g = lane >> 4;
    const int wm   = w & 1, wn = w >> 1;
    const size_t m0 = (size_t)blockIdx.y * 128, n0 = (size_t)blockIdx.x * 128;

    const int srow = lane >> 2;
    const int kc   = lane & 3;

    f32x4 acc[4][4];
#pragma unroll
    for (int i = 0; i < 4; i++)
#pragma unroll
        for (int j = 0; j < 4; j++) acc[i][j] = (f32x4){0.f,0.f,0.f,0.f};

    const short* gA0 = A  + (m0 + w*32 +      srow) * (size_t)K + kc*8;
    const short* gA1 = A  + (m0 + w*32 + 16 + srow) * (size_t)K + kc*8;
    const short* gB0 = Bt + (n0 + w*32 +      srow) * (size_t)K + kc*8;
    const short* gB1 = Bt + (n0 + w*32 + 16 + srow) * (size_t)K + kc*8;
    short* lA0 = &sA[(w*32     )*32];
    short* lA1 = &sA[(w*32 + 16)*32];
    short* lB0 = &sB[(w*32     )*32];
    short* lB1 = &sB[(w*32 + 16)*32];

    for (int k0 = 0; k0 < K; k0 += 32) {
        gl2lds16(gA0 + k0, lA0);
        gl2lds16(gA1 + k0, lA1);
        gl2lds16(gB0 + k0, lB0);
        gl2lds16(gB1 + k0, lB1);
        __syncthreads();

        bf16x8 af[4], bfr[4];
#pragma unroll
        for (int mt = 0; mt < 4; mt++)
            af[mt] = *(const bf16x8*)&sA[(wm*64 + mt*16 + l16)*32 + g*8];
#pragma unroll
        for (int nt = 0; nt < 4; nt++)
            bfr[nt] = *(const bf16x8*)&sB[(wn*64 + nt*16 + l16)*32 + g*8];
#pragma unroll
        for (int mt = 0; mt < 4; mt++)
#pragma unroll
            for (int nt = 0; nt < 4; nt++)
                acc[mt][nt] = __builtin_amdgcn_mfma_f32_16x16x32_bf16(
                                  af[mt], bfr[nt], acc[mt][nt], 0, 0, 0);
        __syncthreads();
    }

#pragma unroll
    for (int mt = 0; mt < 4; mt++) {
        const size_t row0 = m0 + wm*64 + mt*16 + g*4;
#pragma unroll
        for (int nt = 0; nt < 4; nt++) {
            const size_t col = n0 + wn*64 + nt*16 + l16;
            if ((int)col >= vsplit) {           // V part -> transposed bf16 out
                short4 t;
                t.x = f2bs(acc[mt][nt][0] + bias[col]);
                t.y = f2bs(acc[mt][nt][1] + bias[col]);
                t.z = f2bs(acc[mt][nt][2] + bias[col]);
                t.w = f2bs(acc[mt][nt][3] + bias[col]);
                *(short4*)&VtOut[(size_t)(col - vsplit)*MTOK + row0] = t;
            } else {
#pragma unroll
                for (int r = 0; r < 4; r++) {
                    float v = acc[mt][nt][r] + bias[col];
                    if (gelu) v = 0.5f * v * (1.f + erff(v * 0.70710678118f));
                    C[(row0 + r) * (size_t)ldc + col] = f2bs(v);
                }
            }
        }
    }
}

// ---------------------------------------------------------------------------
// 128x64-tile variant for N=768 GEMMs (grid 384 blocks vs 192).
// ---------------------------------------------------------------------------
__global__ __launch_bounds__(256)
void gemm_mfma_n64(const short* __restrict__ A, const short* __restrict__ Bt,
                   const float* __restrict__ bias, short* __restrict__ C, int ldc,
                   int M, int N, int K, int gelu)
{
    __shared__ short sA[128*32];
    __shared__ short sB[64*32];
    const int tid  = threadIdx.x;
    const int w    = tid >> 6;
    const int lane = tid & 63;
    const int l16  = lane & 15, g = lane >> 4;
    const int wm   = w & 1, wn = w >> 1;
    const size_t m0 = (size_t)blockIdx.y * 128, n0 = (size_t)blockIdx.x * 64;

    const int srow = lane >> 2;
    const int kc   = lane & 3;

    f32x4 acc[4][2];
#pragma unroll
    for (int i = 0; i < 4; i++)
#pragma unroll
        for (int j = 0; j < 2; j++) acc[i][j] = (f32x4){0.f,0.f,0.f,0.f};

    const short* gA0 = A  + (m0 + w*32 +      srow) * (size_t)K + kc*8;
    const short* gA1 = A  + (m0 + w*32 + 16 + srow) * (size_t)K + kc*8;
    const short* gB0 = Bt + (n0 + w*16 +      srow) * (size_t)K + kc*8;
    short* lA0 = &sA[(w*32     )*32];
    short* lA1 = &sA[(w*32 + 16)*32];
    short* lB0 = &sB[(w*16     )*32];

    for (int k0 = 0; k0 < K; k0 += 32) {
        gl2lds16(gA0 + k0, lA0);
        gl2lds16(gA1 + k0, lA1);
        gl2lds16(gB0 + k0, lB0);
        __syncthreads();

        bf16x8 af[4], bfr[2];
#pragma unroll
        for (int mt = 0; mt < 4; mt++)
            af[mt] = *(const bf16x8*)&sA[(wm*64 + mt*16 + l16)*32 + g*8];
#pragma unroll
        for (int nt = 0; nt < 2; nt++)
            bfr[nt] = *(const bf16x8*)&sB[(wn*32 + nt*16 + l16)*32 + g*8];
#pragma unroll
        for (int mt = 0; mt < 4; mt++)
#pragma unroll
            for (int nt = 0; nt < 2; nt++)
                acc[mt][nt] = __builtin_amdgcn_mfma_f32_16x16x32_bf16(
                                  af[mt], bfr[nt], acc[mt][nt], 0, 0, 0);
        __syncthreads();
    }

#pragma unroll
    for (int mt = 0; mt < 4; mt++) {
        const size_t row0 = m0 + wm*64 + mt*16 + g*4;
#pragma unroll
        for (int nt = 0; nt < 2; nt++) {
            const size_t col = n0 + wn*32 + nt*16 + l16;
#pragma unroll
            for (int r = 0; r < 4; r++) {
                float v = acc[mt][nt][r] + bias[col];
                if (gelu) v = 0.5f * v * (1.f + erff(v * 0.70710678118f));
                C[(row0 + r) * (size_t)ldc + col] = f2bs(v);
            }
        }
    }
}

// ---------------------------------------------------------------------------
// Flash attention. QK packed [M][1536] (Q|K), Vt [768][M] (precomputed by the
// QKV GEMM epilogue). K and Vt tiles staged cooperatively in LDS (coalesced,
// stride-72 pad, conflict-free b128 reads) -- NO in-kernel transpose.
// bCt = bf16(bias^T * coef) [k][q]: bias for a C-frag column is one bf16x4.
// sP is per-wave rows (write+read same wave, no extra barrier).
// ---------------------------------------------------------------------------
__global__ __launch_bounds__(256)
void attn_fused(const short* __restrict__ QK, const short* __restrict__ Vt,
                const float* __restrict__ mask, const short* __restrict__ bCt,
                short* __restrict__ CTX)
{
    __shared__ short sK[64*72];     // 9.2 KB
    __shared__ short sV[64*72];     // 9.2 KB  (V^T tile: [dim][key])
    __shared__ short sP[64*72];     // 9.2 KB, per-wave rows
    __shared__ float sMask[SS];     // 8 KB

    const int q0  = blockIdx.x * 64;
    const int h   = blockIdx.y;
    const int b   = blockIdx.z;
    const int tid = threadIdx.x;
    const int w   = tid >> 6;
    const int lane = tid & 63;
    const int l16 = lane & 15;
    const int g   = lane >> 4;
    const float scale = 0.125f;

    for (int k = tid; k < SS; k += 256)
        sMask[k] = (1.f - mask[b*SS + k]) * (-10000.0f);

    // Q A-frags (held all kernel)
    const short* qrow = QK + ((size_t)(b*SS) + q0 + w*16 + l16) * 1536 + h*64;
    bf16x8 aQ0 = *(const bf16x8*)(qrow + g*8);
    bf16x8 aQ1 = *(const bf16x8*)(qrow + 32 + g*8);

    f32x4 O[4];
#pragma unroll
    for (int d = 0; d < 4; d++) O[d] = (f32x4){0.f,0.f,0.f,0.f};
    float m_i[4], l_i[4];
#pragma unroll
    for (int r = 0; r < 4; r++) { m_i[r] = -1e30f; l_i[r] = 0.f; }

    const int srow = tid >> 2;      // 0..63
    const int scg  = tid & 3;       // 32B chunk (16 shorts)
    const short* Kst = QK + ((size_t)(b*SS) + srow) * 1536 + 768 + h*64 + scg*16;
    const short* Vst = Vt + (size_t)(h*64 + srow) * MTOK + b*SS + scg*16;
    const short* bCq = bCt;         // [k][q]

    __syncthreads();   // sMask ready

    for (int k0 = 0; k0 < SS; k0 += 64) {
        // ---- stage K tile [key][dim] (coalesced 32B/lane) ----
        {
            bf16x8 t0 = *(const bf16x8*)(Kst + (size_t)k0*1536);
            bf16x8 t1 = *(const bf16x8*)(Kst + (size_t)k0*1536 + 8);
            *(bf16x8*)&sK[srow*72 + scg*16]     = t0;
            *(bf16x8*)&sK[srow*72 + scg*16 + 8] = t1;
        }
        // ---- stage V^T tile [dim][key] (coalesced 32B/lane, NO transpose) ----
        {
            bf16x8 t0 = *(const bf16x8*)(Vst + k0);
            bf16x8 t1 = *(const bf16x8*)(Vst + k0 + 8);
            *(bf16x8*)&sV[srow*72 + scg*16]     = t0;
            *(bf16x8*)&sV[srow*72 + scg*16 + 8] = t1;
        }
        __syncthreads();

        // ---- S = QK^T*scale + bias + mask ----
        float S[4][4];
#pragma unroll
        for (int t16 = 0; t16 < 4; t16++) {
            bf16x8 b0 = *(const bf16x8*)&sK[(t16*16 + l16)*72 + g*8];
            bf16x8 b1 = *(const bf16x8*)&sK[(t16*16 + l16)*72 + 32 + g*8];
            f32x4 c = (f32x4){0.f,0.f,0.f,0.f};
            c = __builtin_amdgcn_mfma_f32_16x16x32_bf16(aQ0, b0, c, 0, 0, 0);
            c = __builtin_amdgcn_mfma_f32_16x16x32_bf16(aQ1, b1, c, 0, 0, 0);
            const int   kcol = k0 + t16*16 + l16;
            const float madd = sMask[kcol];
            bf16x4 bb = *(const bf16x4*)&bCq[(size_t)kcol*SS + q0 + w*16 + g*4];
#pragma unroll
            for (int r = 0; r < 4; r++)
                S[t16][r] = c[r]*scale + bs2f(bb[r]) + madd;
        }

        // ---- online softmax, all in regs ----
#pragma unroll
        for (int r = 0; r < 4; r++) {
            float mx = fmaxf(fmaxf(S[0][r], S[1][r]), fmaxf(S[2][r], S[3][r]));
            mx = fmaxf(mx, __shfl_xor(mx, 1));
            mx = fmaxf(mx, __shfl_xor(mx, 2));
            mx = fmaxf(mx, __shfl_xor(mx, 4));
            mx = fmaxf(mx, __shfl_xor(mx, 8));
            const float mnew  = fmaxf(m_i[r], mx);
            const float alpha = __expf(m_i[r] - mnew);
            float rs = 0.f;
#pragma unroll
            for (int t16 = 0; t16 < 4; t16++) {
                float p = __expf(S[t16][r] - mnew);
                S[t16][r] = p;
                rs += p;
            }
            rs += __shfl_xor(rs, 1);
            rs += __shfl_xor(rs, 2);
            rs += __shfl_xor(rs, 4);
            rs += __shfl_xor(rs, 8);
            l_i[r] = l_i[r]*alpha + rs;
            m_i[r] = mnew;
#pragma unroll
            for (int d = 0; d < 4; d++) O[d][r] *= alpha;
        }

        // ---- P: C-layout -> A-layout via per-wave LDS rows ----
#pragma unroll
        for (int t16 = 0; t16 < 4; t16++)
#pragma unroll
            for (int r = 0; r < 4; r++)
                sP[(w*16 + g*4 + r)*72 + t16*16 + l16] = f2bs(S[t16][r]);

        bf16x8 aP0 = *(const bf16x8*)&sP[(w*16 + l16)*72 + g*8];
        bf16x8 aP1 = *(const bf16x8*)&sP[(w*16 + l16)*72 + 32 + g*8];

        // ---- O += P @ V ----
#pragma unroll
        for (int d = 0; d < 4; d++) {
            bf16x8 v0 = *(const bf16x8*)&sV[(d*16 + l16)*72 + g*8];
            bf16x8 v1 = *(const bf16x8*)&sV[(d*16 + l16)*72 + 32 + g*8];
            O[d] = __builtin_amdgcn_mfma_f32_16x16x32_bf16(aP0, v0, O[d], 0, 0, 0);
            O[d] = __builtin_amdgcn_mfma_f32_16x16x32_bf16(aP1, v1, O[d], 0, 0, 0);
        }
        __syncthreads();   // before next tile restages sK/sV
    }

#pragma unroll
    for (int d = 0; d < 4; d++)
#pragma unroll
        for (int r = 0; r < 4; r++)
            CTX[((size_t)(b*SS) + q0 + w*16 + g*4 + r)*HH + h*64 + d*16 + l16]
                = f2bs(O[d][r] / l_i[r]);
}

// ---------------------------------------------------------------------------
// Out(bf16) = LayerNorm(A + R) * g + beta; optional fp32 copy to OutF.
// ---------------------------------------------------------------------------
__global__ __launch_bounds__(256)
void add_ln(const short* __restrict__ A, const short* __restrict__ R,
            const float* __restrict__ g, const float* __restrict__ beta,
            short* __restrict__ Out, float* __restrict__ OutF)
{
    const int row = blockIdx.x;
    const int tid = threadIdx.x;
    __shared__ float vals[HH];
    __shared__ float rbuf[256];

    float s = 0.f;
    for (int c = tid; c < HH; c += 256) {
        float v = bs2f(A[(size_t)row*HH + c]) + bs2f(R[(size_t)row*HH + c]);
        vals[c] = v;
        s += v;
    }
    rbuf[tid] = s; __syncthreads();
    for (int off = 128; off > 0; off >>= 1) {
        if (tid < off) rbuf[tid] += rbuf[tid + off];
        __syncthreads();
    }
    const float mu = rbuf[0] * (1.f / HH); __syncthreads();

    float s2 = 0.f;
    for (int c = tid; c < HH; c += 256) {
        float d = vals[c] - mu;
        s2 += d * d;
    }
    rbuf[tid] = s2; __syncthreads();
    for (int off = 128; off > 0; off >>= 1) {
        if (tid < off) rbuf[tid] += rbuf[tid + off];
        __syncthreads();
    }
    const float rstd = rsqrtf(rbuf[0] * (1.f / HH) + 1e-12f); __syncthreads();

    for (int c = tid; c < HH; c += 256) {
        float v = (vals[c] - mu) * rstd * g[c] + beta[c];
        Out[(size_t)row*HH + c] = f2bs(v);
        if (OutF) OutF[(size_t)row*HH + c] = v;
    }
}

// ---------------------------------------------------------------------------
extern "C" void kernel_launch(void* const* d_in, const int* in_sizes, int n_in,
                              void* d_out, int out_size, void* d_ws, size_t ws_size,
                              hipStream_t stream)
{
    const float* hs    = (const float*)d_in[0];
    const float* mask  = (const float*)d_in[1];
    const float* biasM = (const float*)d_in[2];
    const float* coef  = (const float*)d_in[3];
    const float* Wq    = (const float*)d_in[4];
    const float* bq    = (const float*)d_in[5];
    const float* Wk    = (const float*)d_in[6];
    const float* bk    = (const float*)d_in[7];
    const float* Wv    = (const float*)d_in[8];
    const float* bv    = (const float*)d_in[9];
    const float* Wo    = (const float*)d_in[10];
    const float* bo    = (const float*)d_in[11];
    const float* ln1g  = (const float*)d_in[12];
    const float* ln1b  = (const float*)d_in[13];
    const float* Wi    = (const float*)d_in[14];
    const float* bi    = (const float*)d_in[15];
    const float* Wo2   = (const float*)d_in[16];
    const float* bo2   = (const float*)d_in[17];
    const float* ln2g  = (const float*)d_in[18];
    const float* ln2b  = (const float*)d_in[19];

    // ---- workspace (74.5 MB) ----
    const size_t sH   = (size_t)MTOK * HH;
    const size_t sQK  = (size_t)MTOK * 1536;
    const size_t sVt  = (size_t)HH * MTOK;
    const size_t WPL  = 7077888;
    short* wt   = (short*)d_ws;
    float* bqkv = (float*)(wt + 2*WPL);
    short* bCt  = (short*)(bqkv + 2*2304);        // bias^T * coef, [k][q]
    short* X    = bCt + (size_t)SS*SS;
    short* X2   = X  + sH;
    short* QK   = X2 + sH;
    short* Vt   = QK + sQK;
    short* CTX  = Vt + sVt;
    short* TMP  = QK;
    short* INTER= QK;
    short* TMP2 = X;

    const dim3 blk(256);

    for (int l = 0; l < NLAYER; l++) {
        short* wl = wt + (size_t)l * WPL;
        short* qkvt = wl;
        short* wot  = wl + 1769472;
        short* wit  = wl + 2359296;
        short* wo2t = wl + 4718592;
        transpose_cvt<<<dim3(24,24), blk, 0, stream>>>(Wq + (size_t)l*HH*HH, qkvt,            HH, HH, nullptr);
        transpose_cvt<<<dim3(24,24), blk, 0, stream>>>(Wk + (size_t)l*HH*HH, qkvt + 768*768,  HH, HH, nullptr);
        transpose_cvt<<<dim3(24,24), blk, 0, stream>>>(Wv + (size_t)l*HH*HH, qkvt + 1536*768, HH, HH, nullptr);
        transpose_cvt<<<dim3(24,24), blk, 0, stream>>>(Wo + (size_t)l*HH*HH, wot,             HH, HH, nullptr);
        transpose_cvt<<<dim3(24,96), blk, 0, stream>>>(Wi + (size_t)l*HH*FFD, wit,            HH, FFD, nullptr);
        transpose_cvt<<<dim3(96,24), blk, 0, stream>>>(Wo2+ (size_t)l*FFD*HH, wo2t,           FFD, HH, nullptr);
        hipMemcpyAsync(bqkv + l*2304,        bq + l*HH, HH*4, hipMemcpyDeviceToDevice, stream);
        hipMemcpyAsync(bqkv + l*2304 + 768,  bk + l*HH, HH*4, hipMemcpyDeviceToDevice, stream);
        hipMemcpyAsync(bqkv + l*2304 + 1536, bv + l*HH, HH*4, hipMemcpyDeviceToDevice, stream);
    }
    // bCt[k][q] = biasM[q][k] * coef  (transpose_cvt: W[k0=q][n0=k] -> Wt[k][q])
    transpose_cvt<<<dim3(SS/32, SS/32), blk, 0, stream>>>(biasM, bCt, SS, SS, coef);
    cvt_bf16<<<dim3((int)((sH + 255)/256)), blk, 0, stream>>>(hs, X, (int)sH);

    const dim3 gQKV(2304/128, MTOK/128);   // [18, 32]
    const dim3 gH64(HH/64,    MTOK/128);   // [12, 32]
    const dim3 gFF (FFD/128,  MTOK/128);   // [24, 32]
    const dim3 gA  (SS/64, NHEAD, BB);     // [32, 12, 2] = 768 blocks
    const int NOSPLIT = 1 << 30;

    for (int l = 0; l < NLAYER; l++) {
        short* wl = wt + (size_t)l * WPL;
        gemm_mfma<<<gQKV, blk, 0, stream>>>(X, wl, bqkv + l*2304, QK, 1536,
                                            MTOK, 2304, HH, 0, Vt, 1536);
        attn_fused<<<gA, blk, 0, stream>>>(QK, Vt, mask, bCt, CTX);
        gemm_mfma_n64<<<gH64, blk, 0, stream>>>(CTX, wl + 1769472, bo + l*HH, TMP, HH,
                                                MTOK, HH, HH, 0);
        add_ln<<<MTOK, blk, 0, stream>>>(TMP, X, ln1g + l*HH, ln1b + l*HH, X2, nullptr);
        gemm_mfma<<<gFF, blk, 0, stream>>>(X2, wl + 2359296, bi + l*FFD, INTER, FFD,
                                           MTOK, FFD, HH, 1, nullptr, NOSPLIT);
        gemm_mfma_n64<<<gH64, blk, 0, stream>>>(INTER, wl + 4718592, bo2 + l*HH, TMP2, HH,
                                                MTOK, HH, FFD, 0);
        add_ln<<<MTOK, blk, 0, stream>>>(TMP2, X2, ln2g + l*HH, ln2b + l*HH, X,
                                         (l == NLAYER-1) ? (float*)d_out : nullptr);
    }
}

// Round 7
// 742.856 us; speedup vs baseline: 1.2090x; 1.0525x over previous
//
#include <hip/hip_runtime.h>
#include <hip/hip_bf16.h>
#include <math.h>

#define BB     2
#define SS     2048
#define HH     768
#define NHEAD  12
#define DHEAD  64
#define FFD    3072
#define NLAYER 2
#define MTOK   (BB*SS)   // 4096 rows

typedef __attribute__((ext_vector_type(8))) short bf16x8;
typedef __attribute__((ext_vector_type(4))) short bf16x4;
typedef __attribute__((ext_vector_type(4))) float f32x4;

__device__ __forceinline__ short f2bs(float f) {
    union { float f; unsigned u; } v; v.f = f;
    unsigned r = v.u + 0x7FFF + ((v.u >> 16) & 1);   // RNE to bf16
    return (short)(r >> 16);
}
__device__ __forceinline__ float bs2f(short s) {
    union { unsigned u; float f; } v; v.u = ((unsigned)(unsigned short)s) << 16;
    return v.f;
}
// async 16B/lane global->LDS (lds dst = wave-uniform base + lane*16)
__device__ __forceinline__ void gl2lds16(const short* g, short* l) {
    __builtin_amdgcn_global_load_lds(
        (const __attribute__((address_space(1))) unsigned int*)g,
        (__attribute__((address_space(3))) unsigned int*)l, 16, 0, 0);
}

// ---------------------------------------------------------------------------
// Prep: batched transpose+cvt. Wt[n*K+k] = bf16(W[k*N+n] * scale).
// Up to 8 same-shape jobs selected by blockIdx.z (pointers passed by value).
// ---------------------------------------------------------------------------
struct TJobs { const float* src[8]; short* dst[8]; };

__global__ __launch_bounds__(256)
void transpose_cvt_batch(TJobs jobs, int K, int N, const float* __restrict__ scalep)
{
    const float* __restrict__ W  = jobs.src[blockIdx.z];
    short* __restrict__ Wt = jobs.dst[blockIdx.z];
    __shared__ short tile[32][33];
    const int k0 = blockIdx.x * 32, n0 = blockIdx.y * 32;
    const int tx = threadIdx.x & 31, ty = threadIdx.x >> 5;
    const float s = scalep ? scalep[0] : 1.f;
#pragma unroll
    for (int i = 0; i < 4; i++)
        tile[ty + i*8][tx] = f2bs(W[(size_t)(k0 + ty + i*8) * N + n0 + tx] * s);
    __syncthreads();
#pragma unroll
    for (int i = 0; i < 4; i++)
        Wt[(size_t)(n0 + ty + i*8) * K + k0 + tx] = tile[tx][ty + i*8];
}

// Prep: dst = bf16(src)
__global__ __launch_bounds__(256)
void cvt_bf16(const float* __restrict__ src, short* __restrict__ dst, int n)
{
    const int i = blockIdx.x * 256 + threadIdx.x;
    if (i < n) dst[i] = f2bs(src[i]);
}

// Prep: bqkv[l*2304 + {0|768|1536} + c] = {bq|bk|bv}[l*768 + c]
__global__ __launch_bounds__(256)
void pack_bias(const float* __restrict__ bq, const float* __restrict__ bk,
               const float* __restrict__ bv, float* __restrict__ bqkv)
{
    const int t = blockIdx.x * 256 + threadIdx.x;
    if (t >= NLAYER * 2304) return;
    const int l = t / 2304, r = t % 2304;
    const float* src = (r < 768) ? bq : (r < 1536 ? bk : bv);
    bqkv[t] = src[l*768 + (r % 768)];
}

// ---------------------------------------------------------------------------
// C[M,N](bf16) = act(A[M,K](bf16) @ Bt[N,K](bf16)^T + bias[N](f32))
// m97 recipe: 128x128 tile, BK=32, 4 waves, 16x16x32 MFMA, global_load_lds.
// Cols >= vsplit are written TRANSPOSED to VtOut[col-vsplit][row] (short4).
// ---------------------------------------------------------------------------
__global__ __launch_bounds__(256)
void gemm_mfma(const short* __restrict__ A, const short* __restrict__ Bt,
               const float* __restrict__ bias, short* __restrict__ C, int ldc,
               int M, int N, int K, int gelu, short* __restrict__ VtOut, int vsplit)
{
    __shared__ short sA[128*32];
    __shared__ short sB[128*32];
    const int tid  = threadIdx.x;
    const int w    = tid >> 6;
    const int lane = tid & 63;
    const int l16  = lane & 15, g = lane >> 4;
    const int wm   = w & 1, wn = w >> 1;
    const size_t m0 = (size_t)blockIdx.y * 128, n0 = (size_t)blockIdx.x * 128;

    const int srow = lane >> 2;
    const int kc   = lane & 3;

    f32x4 acc[4][4];
#pragma unroll
    for (int i = 0; i < 4; i++)
#pragma unroll
        for (int j = 0; j < 4; j++) acc[i][j] = (f32x4){0.f,0.f,0.f,0.f};

    const short* gA0 = A  + (m0 + w*32 +      srow) * (size_t)K + kc*8;
    const short* gA1 = A  + (m0 + w*32 + 16 + srow) * (size_t)K + kc*8;
    const short* gB0 = Bt + (n0 + w*32 +      srow) * (size_t)K + kc*8;
    const short* gB1 = Bt + (n0 + w*32 + 16 + srow) * (size_t)K + kc*8;
    short* lA0 = &sA[(w*32     )*32];
    short* lA1 = &sA[(w*32 + 16)*32];
    short* lB0 = &sB[(w*32     )*32];
    short* lB1 = &sB[(w*32 + 16)*32];

    for (int k0 = 0; k0 < K; k0 += 32) {
        gl2lds16(gA0 + k0, lA0);
        gl2lds16(gA1 + k0, lA1);
        gl2lds16(gB0 + k0, lB0);
        gl2lds16(gB1 + k0, lB1);
        __syncthreads();

        bf16x8 af[4], bfr[4];
#pragma unroll
        for (int mt = 0; mt < 4; mt++)
            af[mt] = *(const bf16x8*)&sA[(wm*64 + mt*16 + l16)*32 + g*8];
#pragma unroll
        for (int nt = 0; nt < 4; nt++)
            bfr[nt] = *(const bf16x8*)&sB[(wn*64 + nt*16 + l16)*32 + g*8];
#pragma unroll
        for (int mt = 0; mt < 4; mt++)
#pragma unroll
            for (int nt = 0; nt < 4; nt++)
                acc[mt][nt] = __builtin_amdgcn_mfma_f32_16x16x32_bf16(
                                  af[mt], bfr[nt], acc[mt][nt], 0, 0, 0);
        __syncthreads();
    }

#pragma unroll
    for (int mt = 0; mt < 4; mt++) {
        const size_t row0 = m0 + wm*64 + mt*16 + g*4;
#pragma unroll
        for (int nt = 0; nt < 4; nt++) {
            const size_t col = n0 + wn*64 + nt*16 + l16;
            if ((int)col >= vsplit) {           // V part -> transposed bf16 out
                short4 t;
                t.x = f2bs(acc[mt][nt][0] + bias[col]);
                t.y = f2bs(acc[mt][nt][1] + bias[col]);
                t.z = f2bs(acc[mt][nt][2] + bias[col]);
                t.w = f2bs(acc[mt][nt][3] + bias[col]);
                *(short4*)&VtOut[(size_t)(col - vsplit)*MTOK + row0] = t;
            } else {
#pragma unroll
                for (int r = 0; r < 4; r++) {
                    float v = acc[mt][nt][r] + bias[col];
                    if (gelu) v = 0.5f * v * (1.f + erff(v * 0.70710678118f));
                    C[(row0 + r) * (size_t)ldc + col] = f2bs(v);
                }
            }
        }
    }
}

// ---------------------------------------------------------------------------
// 128x64-tile variant for N=768 GEMMs (grid 384 blocks vs 192).
// ---------------------------------------------------------------------------
__global__ __launch_bounds__(256)
void gemm_mfma_n64(const short* __restrict__ A, const short* __restrict__ Bt,
                   const float* __restrict__ bias, short* __restrict__ C, int ldc,
                   int M, int N, int K, int gelu)
{
    __shared__ short sA[128*32];
    __shared__ short sB[64*32];
    const int tid  = threadIdx.x;
    const int w    = tid >> 6;
    const int lane = tid & 63;
    const int l16  = lane & 15, g = lane >> 4;
    const int wm   = w & 1, wn = w >> 1;
    const size_t m0 = (size_t)blockIdx.y * 128, n0 = (size_t)blockIdx.x * 64;

    const int srow = lane >> 2;
    const int kc   = lane & 3;

    f32x4 acc[4][2];
#pragma unroll
    for (int i = 0; i < 4; i++)
#pragma unroll
        for (int j = 0; j < 2; j++) acc[i][j] = (f32x4){0.f,0.f,0.f,0.f};

    const short* gA0 = A  + (m0 + w*32 +      srow) * (size_t)K + kc*8;
    const short* gA1 = A  + (m0 + w*32 + 16 + srow) * (size_t)K + kc*8;
    const short* gB0 = Bt + (n0 + w*16 +      srow) * (size_t)K + kc*8;
    short* lA0 = &sA[(w*32     )*32];
    short* lA1 = &sA[(w*32 + 16)*32];
    short* lB0 = &sB[(w*16     )*32];

    for (int k0 = 0; k0 < K; k0 += 32) {
        gl2lds16(gA0 + k0, lA0);
        gl2lds16(gA1 + k0, lA1);
        gl2lds16(gB0 + k0, lB0);
        __syncthreads();

        bf16x8 af[4], bfr[2];
#pragma unroll
        for (int mt = 0; mt < 4; mt++)
            af[mt] = *(const bf16x8*)&sA[(wm*64 + mt*16 + l16)*32 + g*8];
#pragma unroll
        for (int nt = 0; nt < 2; nt++)
            bfr[nt] = *(const bf16x8*)&sB[(wn*32 + nt*16 + l16)*32 + g*8];
#pragma unroll
        for (int mt = 0; mt < 4; mt++)
#pragma unroll
            for (int nt = 0; nt < 2; nt++)
                acc[mt][nt] = __builtin_amdgcn_mfma_f32_16x16x32_bf16(
                                  af[mt], bfr[nt], acc[mt][nt], 0, 0, 0);
        __syncthreads();
    }

#pragma unroll
    for (int mt = 0; mt < 4; mt++) {
        const size_t row0 = m0 + wm*64 + mt*16 + g*4;
#pragma unroll
        for (int nt = 0; nt < 2; nt++) {
            const size_t col = n0 + wn*32 + nt*16 + l16;
#pragma unroll
            for (int r = 0; r < 4; r++) {
                float v = acc[mt][nt][r] + bias[col];
                if (gelu) v = 0.5f * v * (1.f + erff(v * 0.70710678118f));
                C[(row0 + r) * (size_t)ldc + col] = f2bs(v);
            }
        }
    }
}

// ---------------------------------------------------------------------------
// Flash attention, 128-key tiles. QK packed [M][1536] (Q|K), Vt [768][M].
// Per 128 keys: stage sK [128 key][64 dim] + sV [64 dim][128 key] (coalesced,
// bank-spread), QK^T for 8 sub-tiles, ONE online-softmax update, PV in two
// 64-key halves through per-wave sP (no extra barrier). 2 barriers / 128 keys.
// bCt = bf16(bias^T * coef) [k][q] so C-frag bias is one bf16x4 load.
// ---------------------------------------------------------------------------
__global__ __launch_bounds__(256)
void attn_fused(const short* __restrict__ QK, const short* __restrict__ Vt,
                const float* __restrict__ mask, const short* __restrict__ bCt,
                short* __restrict__ CTX)
{
    __shared__ short sK[128*72];    // 18.4 KB  [key][dim], pad 72
    __shared__ short sV[64*136];    // 17.4 KB  [dim][key], pad 136
    __shared__ short sP[64*72];     //  9.2 KB  per-wave rows
    __shared__ float sMask[SS];     //  8  KB

    const int q0  = blockIdx.x * 64;
    const int h   = blockIdx.y;
    const int b   = blockIdx.z;
    const int tid = threadIdx.x;
    const int w   = tid >> 6;
    const int lane = tid & 63;
    const int l16 = lane & 15;
    const int g   = lane >> 4;
    const float scale = 0.125f;

    for (int k = tid; k < SS; k += 256)
        sMask[k] = (1.f - mask[b*SS + k]) * (-10000.0f);

    // Q A-frags (held all kernel)
    const short* qrow = QK + ((size_t)(b*SS) + q0 + w*16 + l16) * 1536 + h*64;
    bf16x8 aQ0 = *(const bf16x8*)(qrow + g*8);
    bf16x8 aQ1 = *(const bf16x8*)(qrow + 32 + g*8);

    f32x4 O[4];
#pragma unroll
    for (int d = 0; d < 4; d++) O[d] = (f32x4){0.f,0.f,0.f,0.f};
    float m_i[4], l_i[4];
#pragma unroll
    for (int r = 0; r < 4; r++) { m_i[r] = -1e30f; l_i[r] = 0.f; }

    // staging maps: 8 (16) consecutive lanes cover one contiguous row
    const int krow = tid >> 3, kch = tid & 7;     // K: 32 rows x 8 chunks /pass
    const int vrow = tid >> 4, vch = tid & 15;    // V: 16 rows x 16 chunks /pass
    const short* Kg = QK + ((size_t)(b*SS) + krow)*1536 + 768 + h*64 + kch*8;
    const short* Vg = Vt + ((size_t)(h*64 + vrow))*MTOK + b*SS + vch*8;

    __syncthreads();   // sMask ready

    for (int k0 = 0; k0 < SS; k0 += 128) {
        // ---- stage K tile [128 key][64 dim] (4 passes of 32 rows) ----
#pragma unroll
        for (int p = 0; p < 4; p++)
            *(bf16x8*)&sK[(p*32 + krow)*72 + kch*8] =
                *(const bf16x8*)(Kg + (size_t)(k0 + p*32)*1536);
        // ---- stage V^T tile [64 dim][128 key] (4 passes of 16 rows) ----
#pragma unroll
        for (int p = 0; p < 4; p++)
            *(bf16x8*)&sV[(p*16 + vrow)*136 + vch*8] =
                *(const bf16x8*)(Vg + (size_t)(p*16)*MTOK + k0);
        __syncthreads();

        // ---- S = QK^T*scale + bias + mask (8 sub-tiles of 16 keys) ----
        float S[8][4];
#pragma unroll
        for (int t = 0; t < 8; t++) {
            bf16x8 b0 = *(const bf16x8*)&sK[(t*16 + l16)*72 + g*8];
            bf16x8 b1 = *(const bf16x8*)&sK[(t*16 + l16)*72 + 32 + g*8];
            f32x4 c = (f32x4){0.f,0.f,0.f,0.f};
            c = __builtin_amdgcn_mfma_f32_16x16x32_bf16(aQ0, b0, c, 0, 0, 0);
            c = __builtin_amdgcn_mfma_f32_16x16x32_bf16(aQ1, b1, c, 0, 0, 0);
            const int   kcol = k0 + t*16 + l16;
            const float madd = sMask[kcol];
            bf16x4 bb = *(const bf16x4*)&bCt[(size_t)kcol*SS + q0 + w*16 + g*4];
#pragma unroll
            for (int r = 0; r < 4; r++)
                S[t][r] = c[r]*scale + bs2f(bb[r]) + madd;
        }

        // ---- ONE online-softmax update per 128 keys ----
#pragma unroll
        for (int r = 0; r < 4; r++) {
            float mx = S[0][r];
#pragma unroll
            for (int t = 1; t < 8; t++) mx = fmaxf(mx, S[t][r]);
            mx = fmaxf(mx, __shfl_xor(mx, 1));
            mx = fmaxf(mx, __shfl_xor(mx, 2));
            mx = fmaxf(mx, __shfl_xor(mx, 4));
            mx = fmaxf(mx, __shfl_xor(mx, 8));
            const float mnew  = fmaxf(m_i[r], mx);
            const float alpha = __expf(m_i[r] - mnew);
            float rs = 0.f;
#pragma unroll
            for (int t = 0; t < 8; t++) {
                float p = __expf(S[t][r] - mnew);
                S[t][r] = p;
                rs += p;
            }
            rs += __shfl_xor(rs, 1);
            rs += __shfl_xor(rs, 2);
            rs += __shfl_xor(rs, 4);
            rs += __shfl_xor(rs, 8);
            l_i[r] = l_i[r]*alpha + rs;
            m_i[r] = mnew;
#pragma unroll
            for (int d = 0; d < 4; d++) O[d][r] *= alpha;
        }

        // ---- PV in two 64-key halves via per-wave sP (in-wave DS order) ----
#pragma unroll
        for (int hh = 0; hh < 2; hh++) {
#pragma unroll
            for (int t4 = 0; t4 < 4; t4++)
#pragma unroll
                for (int r = 0; r < 4; r++)
                    sP[(w*16 + g*4 + r)*72 + t4*16 + l16] = f2bs(S[hh*4 + t4][r]);
            bf16x8 aP0 = *(const bf16x8*)&sP[(w*16 + l16)*72 + g*8];
            bf16x8 aP1 = *(const bf16x8*)&sP[(w*16 + l16)*72 + 32 + g*8];
#pragma unroll
            for (int d = 0; d < 4; d++) {
                bf16x8 v0 = *(const bf16x8*)&sV[(d*16 + l16)*136 + hh*64 + g*8];
                bf16x8 v1 = *(const bf16x8*)&sV[(d*16 + l16)*136 + hh*64 + 32 + g*8];
                O[d] = __builtin_amdgcn_mfma_f32_16x16x32_bf16(aP0, v0, O[d], 0, 0, 0);
                O[d] = __builtin_amdgcn_mfma_f32_16x16x32_bf16(aP1, v1, O[d], 0, 0, 0);
            }
        }
        __syncthreads();   // before next tile restages sK/sV
    }

#pragma unroll
    for (int d = 0; d < 4; d++)
#pragma unroll
        for (int r = 0; r < 4; r++)
            CTX[((size_t)(b*SS) + q0 + w*16 + g*4 + r)*HH + h*64 + d*16 + l16]
                = f2bs(O[d][r] / l_i[r]);
}

// ---------------------------------------------------------------------------
// Out(bf16) = LayerNorm(A + R) * g + beta; optional fp32 copy to OutF.
// One WAVE per row (4 rows / 256-thread block), shfl-only reductions,
// zero __syncthreads. 768 = 64 lanes x 12 elems (3 passes of bf16x4).
// ---------------------------------------------------------------------------
__global__ __launch_bounds__(256)
void add_ln(const short* __restrict__ A, const short* __restrict__ R,
            const float* __restrict__ g, const float* __restrict__ beta,
            short* __restrict__ Out, float* __restrict__ OutF)
{
    const int lane = threadIdx.x & 63;
    const int row  = blockIdx.x * 4 + (threadIdx.x >> 6);
    const size_t base = (size_t)row * HH;

    float v[12];
    float s = 0.f;
#pragma unroll
    for (int p = 0; p < 3; p++) {
        const int c = p*256 + lane*4;
        bf16x4 av = *(const bf16x4*)&A[base + c];
        bf16x4 rv = *(const bf16x4*)&R[base + c];
#pragma unroll
        for (int j = 0; j < 4; j++) {
            float x = bs2f(av[j]) + bs2f(rv[j]);
            v[p*4 + j] = x;
            s += x;
        }
    }
    s += __shfl_xor(s, 1);  s += __shfl_xor(s, 2);  s += __shfl_xor(s, 4);
    s += __shfl_xor(s, 8);  s += __shfl_xor(s, 16); s += __shfl_xor(s, 32);
    const float mu = s * (1.f / HH);

    float s2 = 0.f;
#pragma unroll
    for (int j = 0; j < 12; j++) { float d = v[j] - mu; s2 += d * d; }
    s2 += __shfl_xor(s2, 1);  s2 += __shfl_xor(s2, 2);  s2 += __shfl_xor(s2, 4);
    s2 += __shfl_xor(s2, 8);  s2 += __shfl_xor(s2, 16); s2 += __shfl_xor(s2, 32);
    const float rstd = rsqrtf(s2 * (1.f / HH) + 1e-12f);

#pragma unroll
    for (int p = 0; p < 3; p++) {
        const int c = p*256 + lane*4;
        float4 gv = *(const float4*)&g[c];
        float4 bv = *(const float4*)&beta[c];
        float o0 = (v[p*4+0] - mu) * rstd * gv.x + bv.x;
        float o1 = (v[p*4+1] - mu) * rstd * gv.y + bv.y;
        float o2 = (v[p*4+2] - mu) * rstd * gv.z + bv.z;
        float o3 = (v[p*4+3] - mu) * rstd * gv.w + bv.w;
        bf16x4 ov; ov[0] = f2bs(o0); ov[1] = f2bs(o1); ov[2] = f2bs(o2); ov[3] = f2bs(o3);
        *(bf16x4*)&Out[base + c] = ov;
        if (OutF) {
            float4 of; of.x = o0; of.y = o1; of.z = o2; of.w = o3;
            *(float4*)&OutF[base + c] = of;
        }
    }
}

// ---------------------------------------------------------------------------
extern "C" void kernel_launch(void* const* d_in, const int* in_sizes, int n_in,
                              void* d_out, int out_size, void* d_ws, size_t ws_size,
                              hipStream_t stream)
{
    const float* hs    = (const float*)d_in[0];
    const float* mask  = (const float*)d_in[1];
    const float* biasM = (const float*)d_in[2];
    const float* coef  = (const float*)d_in[3];
    const float* Wq    = (const float*)d_in[4];
    const float* bq    = (const float*)d_in[5];
    const float* Wk    = (const float*)d_in[6];
    const float* bk    = (const float*)d_in[7];
    const float* Wv    = (const float*)d_in[8];
    const float* bv    = (const float*)d_in[9];
    const float* Wo    = (const float*)d_in[10];
    const float* bo    = (const float*)d_in[11];
    const float* ln1g  = (const float*)d_in[12];
    const float* ln1b  = (const float*)d_in[13];
    const float* Wi    = (const float*)d_in[14];
    const float* bi    = (const float*)d_in[15];
    const float* Wo2   = (const float*)d_in[16];
    const float* bo2   = (const float*)d_in[17];
    const float* ln2g  = (const float*)d_in[18];
    const float* ln2b  = (const float*)d_in[19];

    // ---- workspace (74.5 MB) ----
    const size_t sH   = (size_t)MTOK * HH;
    const size_t sQK  = (size_t)MTOK * 1536;
    const size_t sVt  = (size_t)HH * MTOK;
    const size_t WPL  = 7077888;
    short* wt   = (short*)d_ws;
    float* bqkv = (float*)(wt + 2*WPL);
    short* bCt  = (short*)(bqkv + 2*2304);        // bias^T * coef, [k][q]
    short* X    = bCt + (size_t)SS*SS;
    short* X2   = X  + sH;
    short* QK   = X2 + sH;
    short* Vt   = QK + sQK;
    short* CTX  = Vt + sVt;
    short* TMP  = QK;
    short* INTER= QK;
    short* TMP2 = X;

    const dim3 blk(256);

    // ---- prep: batched transposes, bias pack, hs cvt ----
    TJobs jH, jI, jO, jB;
    for (int l = 0; l < NLAYER; l++) {
        short* wl = wt + (size_t)l * WPL;
        jH.src[l*4+0] = Wq + (size_t)l*HH*HH;  jH.dst[l*4+0] = wl;
        jH.src[l*4+1] = Wk + (size_t)l*HH*HH;  jH.dst[l*4+1] = wl + 768*768;
        jH.src[l*4+2] = Wv + (size_t)l*HH*HH;  jH.dst[l*4+2] = wl + 1536*768;
        jH.src[l*4+3] = Wo + (size_t)l*HH*HH;  jH.dst[l*4+3] = wl + 1769472;
        jI.src[l] = Wi  + (size_t)l*HH*FFD;    jI.dst[l] = wl + 2359296;
        jO.src[l] = Wo2 + (size_t)l*FFD*HH;    jO.dst[l] = wl + 4718592;
    }
    jB.src[0] = biasM; jB.dst[0] = bCt;
    transpose_cvt_batch<<<dim3(24,24,8), blk, 0, stream>>>(jH, HH, HH, nullptr);
    transpose_cvt_batch<<<dim3(24,96,2), blk, 0, stream>>>(jI, HH, FFD, nullptr);
    transpose_cvt_batch<<<dim3(96,24,2), blk, 0, stream>>>(jO, FFD, HH, nullptr);
    transpose_cvt_batch<<<dim3(64,64,1), blk, 0, stream>>>(jB, SS, SS, coef);
    pack_bias<<<dim3((NLAYER*2304 + 255)/256), blk, 0, stream>>>(bq, bk, bv, bqkv);
    cvt_bf16<<<dim3((int)((sH + 255)/256)), blk, 0, stream>>>(hs, X, (int)sH);

    const dim3 gQKV(2304/128, MTOK/128);   // [18, 32]
    const dim3 gH64(HH/64,    MTOK/128);   // [12, 32]
    const dim3 gFF (FFD/128,  MTOK/128);   // [24, 32]
    const dim3 gA  (SS/64, NHEAD, BB);     // [32, 12, 2] = 768 blocks
    const dim3 gLN (MTOK/4);               // wave-per-row LN
    const int NOSPLIT = 1 << 30;

    for (int l = 0; l < NLAYER; l++) {
        short* wl = wt + (size_t)l * WPL;
        gemm_mfma<<<gQKV, blk, 0, stream>>>(X, wl, bqkv + l*2304, QK, 1536,
                                            MTOK, 2304, HH, 0, Vt, 1536);
        attn_fused<<<gA, blk, 0, stream>>>(QK, Vt, mask, bCt, CTX);
        gemm_mfma_n64<<<gH64, blk, 0, stream>>>(CTX, wl + 1769472, bo + l*HH, TMP, HH,
                                                MTOK, HH, HH, 0);
        add_ln<<<gLN, blk, 0, stream>>>(TMP, X, ln1g + l*HH, ln1b + l*HH, X2, nullptr);
        gemm_mfma<<<gFF, blk, 0, stream>>>(X2, wl + 2359296, bi + l*FFD, INTER, FFD,
                                           MTOK, FFD, HH, 1, nullptr, NOSPLIT);
        gemm_mfma_n64<<<gH64, blk, 0, stream>>>(INTER, wl + 4718592, bo2 + l*HH, TMP2, HH,
                                                MTOK, HH, FFD, 0);
        add_ln<<<gLN, blk, 0, stream>>>(TMP2, X2, ln2g + l*HH, ln2b + l*HH, X,
                                        (l == NLAYER-1) ? (float*)d_out : nullptr);
    }
}

// Round 8
// 669.772 us; speedup vs baseline: 1.3409x; 1.1091x over previous
//
#include <hip/hip_runtime.h>
#include <hip/hip_bf16.h>
#include <math.h>

#define BB     2
#define SS     2048
#define HH     768
#define NHEAD  12
#define DHEAD  64
#define FFD    3072
#define NLAYER 2
#define MTOK   (BB*SS)   // 4096 rows

typedef __attribute__((ext_vector_type(8))) short bf16x8;
typedef __attribute__((ext_vector_type(4))) short bf16x4;
typedef __attribute__((ext_vector_type(4))) float f32x4;

__device__ __forceinline__ short f2bs(float f) {
    union { float f; unsigned u; } v; v.f = f;
    unsigned r = v.u + 0x7FFF + ((v.u >> 16) & 1);   // RNE to bf16
    return (short)(r >> 16);
}
__device__ __forceinline__ float bs2f(short s) {
    union { unsigned u; float f; } v; v.u = ((unsigned)(unsigned short)s) << 16;
    return v.f;
}
// async 16B/lane global->LDS (lds dst = wave-uniform base + lane*16)
__device__ __forceinline__ void gl2lds16(const short* g, short* l) {
    __builtin_amdgcn_global_load_lds(
        (const __attribute__((address_space(1))) unsigned int*)g,
        (__attribute__((address_space(3))) unsigned int*)l, 16, 0, 0);
}

// ---------------------------------------------------------------------------
// Prep: batched transpose+cvt. Wt[n*K+k] = bf16(W[k*N+n]).
// Up to 8 same-shape jobs selected by blockIdx.z (pointers passed by value).
// ---------------------------------------------------------------------------
struct TJobs { const float* src[8]; short* dst[8]; };

__global__ __launch_bounds__(256)
void transpose_cvt_batch(TJobs jobs, int K, int N)
{
    const float* __restrict__ W  = jobs.src[blockIdx.z];
    short* __restrict__ Wt = jobs.dst[blockIdx.z];
    __shared__ short tile[32][33];
    const int k0 = blockIdx.x * 32, n0 = blockIdx.y * 32;
    const int tx = threadIdx.x & 31, ty = threadIdx.x >> 5;
#pragma unroll
    for (int i = 0; i < 4; i++)
        tile[ty + i*8][tx] = f2bs(W[(size_t)(k0 + ty + i*8) * N + n0 + tx]);
    __syncthreads();
#pragma unroll
    for (int i = 0; i < 4; i++)
        Wt[(size_t)(n0 + ty + i*8) * K + k0 + tx] = tile[tx][ty + i*8];
}

// Prep: dst = bf16(src)
__global__ __launch_bounds__(256)
void cvt_bf16(const float* __restrict__ src, short* __restrict__ dst, int n)
{
    const int i = blockIdx.x * 256 + threadIdx.x;
    if (i < n) dst[i] = f2bs(src[i]);
}

// Prep: bqkv[l*2304 + {0|768|1536} + c] = {bq|bk|bv}[l*768 + c]
__global__ __launch_bounds__(256)
void pack_bias(const float* __restrict__ bq, const float* __restrict__ bk,
               const float* __restrict__ bv, float* __restrict__ bqkv)
{
    const int t = blockIdx.x * 256 + threadIdx.x;
    if (t >= NLAYER * 2304) return;
    const int l = t / 2304, r = t % 2304;
    const float* src = (r < 768) ? bq : (r < 1536 ? bk : bv);
    bqkv[t] = src[l*768 + (r % 768)];
}

// ---------------------------------------------------------------------------
// Prep: bias+mask in MFMA C-fragment order.
// bFrag[((((b*32+qb)*4 + w)*128 + kt)*64 + lane)*4 + r]
//   = bf16( biasM[qb*64 + w*16 + (lane>>4)*4 + r][kt*16 + (lane&15)]*coef
//           + (1-mask[b][kt*16 + (lane&15)])*(-10000) )
// Grid (32 qb, 16 k-chunks of 128), block 256. Coalesced in, coalesced out.
// ---------------------------------------------------------------------------
__global__ __launch_bounds__(256)
void bias_frag_prep(const float* __restrict__ biasM, const float* __restrict__ mask,
                    const float* __restrict__ coefp, short* __restrict__ bFrag)
{
    __shared__ float tile[64][129];   // 33 KB
    const int tid = threadIdx.x;
    const int qb = blockIdx.x, q0 = qb*64, k0 = blockIdx.y*128;
#pragma unroll
    for (int p = 0; p < 8; p++) {
        const int row = p*8 + (tid >> 5);
        const int col = (tid & 31) * 4;
        float4 v = *(const float4*)&biasM[(size_t)(q0 + row)*SS + k0 + col];
        tile[row][col+0] = v.x; tile[row][col+1] = v.y;
        tile[row][col+2] = v.z; tile[row][col+3] = v.w;
    }
    __syncthreads();
    const float coef = coefp[0];
    const int lane = tid & 63, w = tid >> 6;
    const int qrow = w*16 + ((lane >> 4) << 2);
    const int kcol = lane & 15;
#pragma unroll
    for (int b = 0; b < BB; b++) {
#pragma unroll
        for (int kt = 0; kt < 8; kt++) {
            const float madd = (1.f - mask[b*SS + k0 + kt*16 + kcol]) * (-10000.0f);
            bf16x4 o;
#pragma unroll
            for (int r = 0; r < 4; r++)
                o[r] = f2bs(tile[qrow + r][kt*16 + kcol] * coef + madd);
            const size_t idx = ((((size_t)b*32 + qb)*4 + w)*128 + (k0>>4) + kt)*256 + lane*4;
            *(bf16x4*)&bFrag[idx] = o;
        }
    }
}

// ---------------------------------------------------------------------------
// C[M,N](bf16) = act(A[M,K](bf16) @ Bt[N,K](bf16)^T + bias[N](f32))
// m97 recipe: 128x128 tile, BK=32, 4 waves, 16x16x32 MFMA, global_load_lds.
// Cols >= vsplit are written TRANSPOSED to VtOut[col-vsplit][row] (short4).
// ---------------------------------------------------------------------------
__global__ __launch_bounds__(256)
void gemm_mfma(const short* __restrict__ A, const short* __restrict__ Bt,
               const float* __restrict__ bias, short* __restrict__ C, int ldc,
               int M, int N, int K, int gelu, short* __restrict__ VtOut, int vsplit)
{
    __shared__ short sA[128*32];
    __shared__ short sB[128*32];
    const int tid  = threadIdx.x;
    const int w    = tid >> 6;
    const int lane = tid & 63;
    const int l16  = lane & 15, g = lane >> 4;
    const int wm   = w & 1, wn = w >> 1;
    const size_t m0 = (size_t)blockIdx.y * 128, n0 = (size_t)blockIdx.x * 128;

    const int srow = lane >> 2;
    const int kc   = lane & 3;

    f32x4 acc[4][4];
#pragma unroll
    for (int i = 0; i < 4; i++)
#pragma unroll
        for (int j = 0; j < 4; j++) acc[i][j] = (f32x4){0.f,0.f,0.f,0.f};

    const short* gA0 = A  + (m0 + w*32 +      srow) * (size_t)K + kc*8;
    const short* gA1 = A  + (m0 + w*32 + 16 + srow) * (size_t)K + kc*8;
    const short* gB0 = Bt + (n0 + w*32 +      srow) * (size_t)K + kc*8;
    const short* gB1 = Bt + (n0 + w*32 + 16 + srow) * (size_t)K + kc*8;
    short* lA0 = &sA[(w*32     )*32];
    short* lA1 = &sA[(w*32 + 16)*32];
    short* lB0 = &sB[(w*32     )*32];
    short* lB1 = &sB[(w*32 + 16)*32];

    for (int k0 = 0; k0 < K; k0 += 32) {
        gl2lds16(gA0 + k0, lA0);
        gl2lds16(gA1 + k0, lA1);
        gl2lds16(gB0 + k0, lB0);
        gl2lds16(gB1 + k0, lB1);
        __syncthreads();

        bf16x8 af[4], bfr[4];
#pragma unroll
        for (int mt = 0; mt < 4; mt++)
            af[mt] = *(const bf16x8*)&sA[(wm*64 + mt*16 + l16)*32 + g*8];
#pragma unroll
        for (int nt = 0; nt < 4; nt++)
            bfr[nt] = *(const bf16x8*)&sB[(wn*64 + nt*16 + l16)*32 + g*8];
#pragma unroll
        for (int mt = 0; mt < 4; mt++)
#pragma unroll
            for (int nt = 0; nt < 4; nt++)
                acc[mt][nt] = __builtin_amdgcn_mfma_f32_16x16x32_bf16(
                                  af[mt], bfr[nt], acc[mt][nt], 0, 0, 0);
        __syncthreads();
    }

#pragma unroll
    for (int mt = 0; mt < 4; mt++) {
        const size_t row0 = m0 + wm*64 + mt*16 + g*4;
#pragma unroll
        for (int nt = 0; nt < 4; nt++) {
            const size_t col = n0 + wn*64 + nt*16 + l16;
            if ((int)col >= vsplit) {           // V part -> transposed bf16 out
                short4 t;
                t.x = f2bs(acc[mt][nt][0] + bias[col]);
                t.y = f2bs(acc[mt][nt][1] + bias[col]);
                t.z = f2bs(acc[mt][nt][2] + bias[col]);
                t.w = f2bs(acc[mt][nt][3] + bias[col]);
                *(short4*)&VtOut[(size_t)(col - vsplit)*MTOK + row0] = t;
            } else {
#pragma unroll
                for (int r = 0; r < 4; r++) {
                    float v = acc[mt][nt][r] + bias[col];
                    if (gelu) v = 0.5f * v * (1.f + erff(v * 0.70710678118f));
                    C[(row0 + r) * (size_t)ldc + col] = f2bs(v);
                }
            }
        }
    }
}

// ---------------------------------------------------------------------------
// 128x64-tile variant for N=768 GEMMs (grid 384 blocks vs 192).
// ---------------------------------------------------------------------------
__global__ __launch_bounds__(256)
void gemm_mfma_n64(const short* __restrict__ A, const short* __restrict__ Bt,
                   const float* __restrict__ bias, short* __restrict__ C, int ldc,
                   int M, int N, int K, int gelu)
{
    __shared__ short sA[128*32];
    __shared__ short sB[64*32];
    const int tid  = threadIdx.x;
    const int w    = tid >> 6;
    const int lane = tid & 63;
    const int l16  = lane & 15, g = lane >> 4;
    const int wm   = w & 1, wn = w >> 1;
    const size_t m0 = (size_t)blockIdx.y * 128, n0 = (size_t)blockIdx.x * 64;

    const int srow = lane >> 2;
    const int kc   = lane & 3;

    f32x4 acc[4][2];
#pragma unroll
    for (int i = 0; i < 4; i++)
#pragma unroll
        for (int j = 0; j < 2; j++) acc[i][j] = (f32x4){0.f,0.f,0.f,0.f};

    const short* gA0 = A  + (m0 + w*32 +      srow) * (size_t)K + kc*8;
    const short* gA1 = A  + (m0 + w*32 + 16 + srow) * (size_t)K + kc*8;
    const short* gB0 = Bt + (n0 + w*16 +      srow) * (size_t)K + kc*8;
    short* lA0 = &sA[(w*32     )*32];
    short* lA1 = &sA[(w*32 + 16)*32];
    short* lB0 = &sB[(w*16     )*32];

    for (int k0 = 0; k0 < K; k0 += 32) {
        gl2lds16(gA0 + k0, lA0);
        gl2lds16(gA1 + k0, lA1);
        gl2lds16(gB0 + k0, lB0);
        __syncthreads();

        bf16x8 af[4], bfr[2];
#pragma unroll
        for (int mt = 0; mt < 4; mt++)
            af[mt] = *(const bf16x8*)&sA[(wm*64 + mt*16 + l16)*32 + g*8];
#pragma unroll
        for (int nt = 0; nt < 2; nt++)
            bfr[nt] = *(const bf16x8*)&sB[(wn*32 + nt*16 + l16)*32 + g*8];
#pragma unroll
        for (int mt = 0; mt < 4; mt++)
#pragma unroll
            for (int nt = 0; nt < 2; nt++)
                acc[mt][nt] = __builtin_amdgcn_mfma_f32_16x16x32_bf16(
                                  af[mt], bfr[nt], acc[mt][nt], 0, 0, 0);
        __syncthreads();
    }

#pragma unroll
    for (int mt = 0; mt < 4; mt++) {
        const size_t row0 = m0 + wm*64 + mt*16 + g*4;
#pragma unroll
        for (int nt = 0; nt < 2; nt++) {
            const size_t col = n0 + wn*32 + nt*16 + l16;
#pragma unroll
            for (int r = 0; r < 4; r++) {
                float v = acc[mt][nt][r] + bias[col];
                if (gelu) v = 0.5f * v * (1.f + erff(v * 0.70710678118f));
                C[(row0 + r) * (size_t)ldc + col] = f2bs(v);
            }
        }
    }
}

// ---------------------------------------------------------------------------
// Flash attention, 128-key tiles, software-pipelined staging.
// QK packed [M][1536] (Q|K), Vt [768][M], bFrag = bias+mask in C-frag order.
// Loop: write prefetched regs->LDS, barrier, prefetch NEXT tile to regs
// (overlaps compute), QK^T (8 subtiles), one online-softmax update,
// PV in two 64-key halves via per-wave sP. Bias load = coalesced 8B/lane.
// ---------------------------------------------------------------------------
__global__ __launch_bounds__(256)
void attn_fused(const short* __restrict__ QK, const short* __restrict__ Vt,
                const short* __restrict__ bFrag, short* __restrict__ CTX)
{
    __shared__ short sK[128*72];    // 18.4 KB  [key][dim]
    __shared__ short sV[64*136];    // 17.4 KB  [dim][key]
    __shared__ short sP[64*72];     //  9.2 KB  per-wave rows

    const int qb  = blockIdx.x;
    const int q0  = qb * 64;
    const int h   = blockIdx.y;
    const int b   = blockIdx.z;
    const int tid = threadIdx.x;
    const int w   = tid >> 6;
    const int lane = tid & 63;
    const int l16 = lane & 15;
    const int g   = lane >> 4;
    const float scale = 0.125f;

    // Q A-frags (held all kernel)
    const short* qrow = QK + ((size_t)(b*SS) + q0 + w*16 + l16) * 1536 + h*64;
    bf16x8 aQ0 = *(const bf16x8*)(qrow + g*8);
    bf16x8 aQ1 = *(const bf16x8*)(qrow + 32 + g*8);

    f32x4 O[4];
#pragma unroll
    for (int d = 0; d < 4; d++) O[d] = (f32x4){0.f,0.f,0.f,0.f};
    float m_i[4], l_i[4];
#pragma unroll
    for (int r = 0; r < 4; r++) { m_i[r] = -1e30f; l_i[r] = 0.f; }

    // staging maps: 8 (16) consecutive lanes cover one contiguous row
    const int krow = tid >> 3, kch = tid & 7;     // K: 32 rows x 8 chunks /pass
    const int vrow = tid >> 4, vch = tid & 15;    // V: 16 rows x 16 chunks /pass
    const short* Kg = QK + ((size_t)(b*SS) + krow)*1536 + 768 + h*64 + kch*8;
    const short* Vg = Vt + ((size_t)(h*64 + vrow))*MTOK + b*SS + vch*8;
    // bias frags: per wave, per k-subtile: one coalesced bf16x4 at lane*4
    const short* bF = bFrag + ((((size_t)b*32 + qb)*4 + w)*128)*256 + lane*4;

    // prologue prefetch (tile 0)
    bf16x8 kreg[4], vreg[4];
#pragma unroll
    for (int p = 0; p < 4; p++) {
        kreg[p] = *(const bf16x8*)(Kg + (size_t)(p*32)*1536);
        vreg[p] = *(const bf16x8*)(Vg + (size_t)(p*16)*MTOK);
    }

    for (int k0 = 0; k0 < SS; k0 += 128) {
        // ---- staged regs -> LDS ----
#pragma unroll
        for (int p = 0; p < 4; p++) {
            *(bf16x8*)&sK[(p*32 + krow)*72 + kch*8]   = kreg[p];
            *(bf16x8*)&sV[(p*16 + vrow)*136 + vch*8]  = vreg[p];
        }
        __syncthreads();

        // ---- prefetch next tile (overlaps with compute below) ----
        if (k0 + 128 < SS) {
#pragma unroll
            for (int p = 0; p < 4; p++) {
                kreg[p] = *(const bf16x8*)(Kg + (size_t)(k0 + 128 + p*32)*1536);
                vreg[p] = *(const bf16x8*)(Vg + (size_t)(p*16)*MTOK + k0 + 128);
            }
        }

        // ---- S = QK^T*scale + (bias+mask frag) ----
        float S[8][4];
        const short* bFt = bF + ((size_t)(k0 >> 4))*256;
#pragma unroll
        for (int t = 0; t < 8; t++) {
            bf16x8 b0 = *(const bf16x8*)&sK[(t*16 + l16)*72 + g*8];
            bf16x8 b1 = *(const bf16x8*)&sK[(t*16 + l16)*72 + 32 + g*8];
            f32x4 c = (f32x4){0.f,0.f,0.f,0.f};
            c = __builtin_amdgcn_mfma_f32_16x16x32_bf16(aQ0, b0, c, 0, 0, 0);
            c = __builtin_amdgcn_mfma_f32_16x16x32_bf16(aQ1, b1, c, 0, 0, 0);
            bf16x4 bb = *(const bf16x4*)(bFt + (size_t)t*256);
#pragma unroll
            for (int r = 0; r < 4; r++)
                S[t][r] = c[r]*scale + bs2f(bb[r]);
        }

        // ---- ONE online-softmax update per 128 keys ----
#pragma unroll
        for (int r = 0; r < 4; r++) {
            float mx = S[0][r];
#pragma unroll
            for (int t = 1; t < 8; t++) mx = fmaxf(mx, S[t][r]);
            mx = fmaxf(mx, __shfl_xor(mx, 1));
            mx = fmaxf(mx, __shfl_xor(mx, 2));
            mx = fmaxf(mx, __shfl_xor(mx, 4));
            mx = fmaxf(mx, __shfl_xor(mx, 8));
            const float mnew  = fmaxf(m_i[r], mx);
            const float alpha = __expf(m_i[r] - mnew);
            float rs = 0.f;
#pragma unroll
            for (int t = 0; t < 8; t++) {
                float p = __expf(S[t][r] - mnew);
                S[t][r] = p;
                rs += p;
            }
            rs += __shfl_xor(rs, 1);
            rs += __shfl_xor(rs, 2);
            rs += __shfl_xor(rs, 4);
            rs += __shfl_xor(rs, 8);
            l_i[r] = l_i[r]*alpha + rs;
            m_i[r] = mnew;
#pragma unroll
            for (int d = 0; d < 4; d++) O[d][r] *= alpha;
        }

        // ---- PV in two 64-key halves via per-wave sP ----
#pragma unroll
        for (int hh = 0; hh < 2; hh++) {
#pragma unroll
            for (int t4 = 0; t4 < 4; t4++)
#pragma unroll
                for (int r = 0; r < 4; r++)
                    sP[(w*16 + g*4 + r)*72 + t4*16 + l16] = f2bs(S[hh*4 + t4][r]);
            bf16x8 aP0 = *(const bf16x8*)&sP[(w*16 + l16)*72 + g*8];
            bf16x8 aP1 = *(const bf16x8*)&sP[(w*16 + l16)*72 + 32 + g*8];
#pragma unroll
            for (int d = 0; d < 4; d++) {
                bf16x8 v0 = *(const bf16x8*)&sV[(d*16 + l16)*136 + hh*64 + g*8];
                bf16x8 v1 = *(const bf16x8*)&sV[(d*16 + l16)*136 + hh*64 + 32 + g*8];
                O[d] = __builtin_amdgcn_mfma_f32_16x16x32_bf16(aP0, v0, O[d], 0, 0, 0);
                O[d] = __builtin_amdgcn_mfma_f32_16x16x32_bf16(aP1, v1, O[d], 0, 0, 0);
            }
        }
        __syncthreads();   // before next tile restages sK/sV
    }

#pragma unroll
    for (int d = 0; d < 4; d++)
#pragma unroll
        for (int r = 0; r < 4; r++)
            CTX[((size_t)(b*SS) + q0 + w*16 + g*4 + r)*HH + h*64 + d*16 + l16]
                = f2bs(O[d][r] / l_i[r]);
}

// ---------------------------------------------------------------------------
// Out(bf16) = LayerNorm(A + R) * g + beta; optional fp32 copy to OutF.
// One WAVE per row, shfl-only reductions, zero __syncthreads.
// ---------------------------------------------------------------------------
__global__ __launch_bounds__(256)
void add_ln(const short* __restrict__ A, const short* __restrict__ R,
            const float* __restrict__ g, const float* __restrict__ beta,
            short* __restrict__ Out, float* __restrict__ OutF)
{
    const int lane = threadIdx.x & 63;
    const int row  = blockIdx.x * 4 + (threadIdx.x >> 6);
    const size_t base = (size_t)row * HH;

    float v[12];
    float s = 0.f;
#pragma unroll
    for (int p = 0; p < 3; p++) {
        const int c = p*256 + lane*4;
        bf16x4 av = *(const bf16x4*)&A[base + c];
        bf16x4 rv = *(const bf16x4*)&R[base + c];
#pragma unroll
        for (int j = 0; j < 4; j++) {
            float x = bs2f(av[j]) + bs2f(rv[j]);
            v[p*4 + j] = x;
            s += x;
        }
    }
    s += __shfl_xor(s, 1);  s += __shfl_xor(s, 2);  s += __shfl_xor(s, 4);
    s += __shfl_xor(s, 8);  s += __shfl_xor(s, 16); s += __shfl_xor(s, 32);
    const float mu = s * (1.f / HH);

    float s2 = 0.f;
#pragma unroll
    for (int j = 0; j < 12; j++) { float d = v[j] - mu; s2 += d * d; }
    s2 += __shfl_xor(s2, 1);  s2 += __shfl_xor(s2, 2);  s2 += __shfl_xor(s2, 4);
    s2 += __shfl_xor(s2, 8);  s2 += __shfl_xor(s2, 16); s2 += __shfl_xor(s2, 32);
    const float rstd = rsqrtf(s2 * (1.f / HH) + 1e-12f);

#pragma unroll
    for (int p = 0; p < 3; p++) {
        const int c = p*256 + lane*4;
        float4 gv = *(const float4*)&g[c];
        float4 bv = *(const float4*)&beta[c];
        float o0 = (v[p*4+0] - mu) * rstd * gv.x + bv.x;
        float o1 = (v[p*4+1] - mu) * rstd * gv.y + bv.y;
        float o2 = (v[p*4+2] - mu) * rstd * gv.z + bv.z;
        float o3 = (v[p*4+3] - mu) * rstd * gv.w + bv.w;
        bf16x4 ov; ov[0] = f2bs(o0); ov[1] = f2bs(o1); ov[2] = f2bs(o2); ov[3] = f2bs(o3);
        *(bf16x4*)&Out[base + c] = ov;
        if (OutF) {
            float4 of; of.x = o0; of.y = o1; of.z = o2; of.w = o3;
            *(float4*)&OutF[base + c] = of;
        }
    }
}

// ---------------------------------------------------------------------------
extern "C" void kernel_launch(void* const* d_in, const int* in_sizes, int n_in,
                              void* d_out, int out_size, void* d_ws, size_t ws_size,
                              hipStream_t stream)
{
    const float* hs    = (const float*)d_in[0];
    const float* mask  = (const float*)d_in[1];
    const float* biasM = (const float*)d_in[2];
    const float* coef  = (const float*)d_in[3];
    const float* Wq    = (const float*)d_in[4];
    const float* bq    = (const float*)d_in[5];
    const float* Wk    = (const float*)d_in[6];
    const float* bk    = (const float*)d_in[7];
    const float* Wv    = (const float*)d_in[8];
    const float* bv    = (const float*)d_in[9];
    const float* Wo    = (const float*)d_in[10];
    const float* bo    = (const float*)d_in[11];
    const float* ln1g  = (const float*)d_in[12];
    const float* ln1b  = (const float*)d_in[13];
    const float* Wi    = (const float*)d_in[14];
    const float* bi    = (const float*)d_in[15];
    const float* Wo2   = (const float*)d_in[16];
    const float* bo2   = (const float*)d_in[17];
    const float* ln2g  = (const float*)d_in[18];
    const float* ln2b  = (const float*)d_in[19];

    // ---- workspace (~83 MB; 138 MB proven available in R2) ----
    const size_t sH   = (size_t)MTOK * HH;
    const size_t sQK  = (size_t)MTOK * 1536;
    const size_t sVt  = (size_t)HH * MTOK;
    const size_t WPL  = 7077888;
    short* wt    = (short*)d_ws;
    float* bqkv  = (float*)(wt + 2*WPL);
    short* bFrag = (short*)(bqkv + 2*2304);       // [2*SS*SS] bias+mask C-frags
    short* X     = bFrag + (size_t)2*SS*SS;
    short* X2    = X  + sH;
    short* QK    = X2 + sH;
    short* Vt    = QK + sQK;
    short* CTX   = Vt + sVt;
    short* TMP   = QK;
    short* INTER = QK;
    short* TMP2  = X;

    const dim3 blk(256);

    // ---- prep: batched transposes, bias frags, bias pack, hs cvt ----
    TJobs jH, jI, jO;
    for (int l = 0; l < NLAYER; l++) {
        short* wl = wt + (size_t)l * WPL;
        jH.src[l*4+0] = Wq + (size_t)l*HH*HH;  jH.dst[l*4+0] = wl;
        jH.src[l*4+1] = Wk + (size_t)l*HH*HH;  jH.dst[l*4+1] = wl + 768*768;
        jH.src[l*4+2] = Wv + (size_t)l*HH*HH;  jH.dst[l*4+2] = wl + 1536*768;
        jH.src[l*4+3] = Wo + (size_t)l*HH*HH;  jH.dst[l*4+3] = wl + 1769472;
        jI.src[l] = Wi  + (size_t)l*HH*FFD;    jI.dst[l] = wl + 2359296;
        jO.src[l] = Wo2 + (size_t)l*FFD*HH;    jO.dst[l] = wl + 4718592;
    }
    transpose_cvt_batch<<<dim3(24,24,8), blk, 0, stream>>>(jH, HH, HH);
    transpose_cvt_batch<<<dim3(24,96,2), blk, 0, stream>>>(jI, HH, FFD);
    transpose_cvt_batch<<<dim3(96,24,2), blk, 0, stream>>>(jO, FFD, HH);
    bias_frag_prep<<<dim3(SS/64, SS/128), blk, 0, stream>>>(biasM, mask, coef, bFrag);
    pack_bias<<<dim3((NLAYER*2304 + 255)/256), blk, 0, stream>>>(bq, bk, bv, bqkv);
    cvt_bf16<<<dim3((int)((sH + 255)/256)), blk, 0, stream>>>(hs, X, (int)sH);

    const dim3 gQKV(2304/128, MTOK/128);   // [18, 32]
    const dim3 gH64(HH/64,    MTOK/128);   // [12, 32]
    const dim3 gFF (FFD/128,  MTOK/128);   // [24, 32]
    const dim3 gA  (SS/64, NHEAD, BB);     // [32, 12, 2] = 768 blocks
    const dim3 gLN (MTOK/4);               // wave-per-row LN
    const int NOSPLIT = 1 << 30;

    for (int l = 0; l < NLAYER; l++) {
        short* wl = wt + (size_t)l * WPL;
        gemm_mfma<<<gQKV, blk, 0, stream>>>(X, wl, bqkv + l*2304, QK, 1536,
                                            MTOK, 2304, HH, 0, Vt, 1536);
        attn_fused<<<gA, blk, 0, stream>>>(QK, Vt, bFrag, CTX);
        gemm_mfma_n64<<<gH64, blk, 0, stream>>>(CTX, wl + 1769472, bo + l*HH, TMP, HH,
                                                MTOK, HH, HH, 0);
        add_ln<<<gLN, blk, 0, stream>>>(TMP, X, ln1g + l*HH, ln1b + l*HH, X2, nullptr);
        gemm_mfma<<<gFF, blk, 0, stream>>>(X2, wl + 2359296, bi + l*FFD, INTER, FFD,
                                           MTOK, FFD, HH, 1, nullptr, NOSPLIT);
        gemm_mfma_n64<<<gH64, blk, 0, stream>>>(INTER, wl + 4718592, bo2 + l*HH, TMP2, HH,
                                                MTOK, HH, FFD, 0);
        add_ln<<<gLN, blk, 0, stream>>>(TMP2, X2, ln2g + l*HH, ln2b + l*HH, X,
                                        (l == NLAYER-1) ? (float*)d_out : nullptr);
    }
}